// Round 23
// baseline (124.777 us; speedup 1.0000x reference)
//
#include <hip/hip_runtime.h>

#define Bsz 8
#define Lx 4096
#define DM 64
#define DI 128
#define NS 16
#define RK 4
#define KC 4
#define NC 64
#define CT 64

typedef __attribute__((ext_vector_type(8))) __bf16 bf16x8v;
typedef __attribute__((ext_vector_type(4))) __bf16 bf16x4v;
typedef __attribute__((ext_vector_type(4))) float f32x4;

__device__ __forceinline__ float fsig(float x){ return 1.f/(1.f+__expf(-x)); }
__device__ __forceinline__ float dot4(float4 a, float4 b){
  return fmaf(a.x,b.x, fmaf(a.y,b.y, fmaf(a.z,b.z, a.w*b.w)));
}
// powers e1^(n0+1)..e1^(n0+8), log-depth
__device__ __forceinline__ void pow8(float e1, int half, float p[8]){
  float e2=e1*e1, e4=e2*e2, e8=e4*e4;
  if (half){
    p[0]=e8*e1; p[1]=e8*e2; p[2]=p[1]*e1; p[3]=e8*e4;
    p[4]=p[3]*e1; p[5]=p[3]*e2; p[6]=p[5]*e1; p[7]=e8*e8;
  } else {
    p[0]=e1; p[1]=e2; p[2]=e2*e1; p[3]=e4;
    p[4]=e4*e1; p[5]=e4*e2; p[6]=p[5]*e1; p[7]=e8;
  }
}

// ---------------------------------------------------------------------------
// A1 v13: round-20 structure + VECTORIZED conv/dt phases (float4 along d).
// xi fp32 region stride 132 (float4-aligned); dtl @ uA[4620]; uA 4880 floats.
// LDS 35904 B -> 4 blocks/CU.
// ---------------------------------------------------------------------------
__global__ __launch_bounds__(512) void a1_front(
    const float* __restrict__ x, const float* __restrict__ ln_g, const float* __restrict__ ln_b,
    const float* __restrict__ in_w, const float* __restrict__ conv_w, const float* __restrict__ conv_b,
    const float* __restrict__ xp_w, const float* __restrict__ dtp_w, const float* __restrict__ dt_b,
    float* __restrict__ xcg, float* __restrict__ dtg, float* __restrict__ zg,
    float* __restrict__ Bg, float* __restrict__ Cg)
{
  __shared__ float uA[4880];   // 19520 B
  __shared__ float uB[4096];   // 16384 B
  const int tid = threadIdx.x;
  const int bx = blockIdx.x;
  const int tile = bx & 63;
  const int i = (bx >> 6) & 1;
  const int b = bx >> 7;
  const int l0 = tile * 64;
  const size_t rbase = (size_t)(b*2+i)*Lx + l0;
  const int lane = tid & 63, wv = tid >> 6;

  // ---- P1: LN -> bf16 X (uA swz, rows 0..66) ----
  {
    const float gg = ln_g[lane], bb = ln_b[lane];
    for (int lr = wv; lr < 67; lr += 8) {
      float v = 0.f;
      int l = l0 - 3 + lr;
      if (l >= 0) {
        int pl = i ? (Lx-1-l) : l;
        v = x[((size_t)b*Lx + pl)*DM + lane];
        float s = v, s2 = v*v;
        #pragma unroll
        for (int off=32; off; off>>=1){ s += __shfl_xor(s,off); s2 += __shfl_xor(s2,off); }
        float mu = s * (1.f/DM);
        float rs = rsqrtf(s2*(1.f/DM) - mu*mu + 1e-5f);
        v = (v-mu)*rs*gg + bb;
      }
      *(__bf16*)((char*)uA + ((lr*128 + lane*2) ^ ((lr&7)<<4))) = (__bf16)v;
    }
  }
  __syncthreads();

  // ---- P2: in_proj MFMA, W staged in two 128-ch halves ----
  f32x4 acc[5][2];
  {
    f32x4 z4v = {0.f, 0.f, 0.f, 0.f};
    #pragma unroll
    for (int mt=0; mt<5; ++mt){ acc[mt][0] = z4v; acc[mt][1] = z4v; }
    #pragma unroll
    for (int p = 0; p < 2; ++p) {
      #pragma unroll
      for (int it=0; it<4; ++it) {
        int g = it*512 + tid;
        int c = g >> 4, q = g & 15;
        float4 w = *(const float4*)(in_w + ((size_t)(i*2*DI) + p*DI + c)*DM + q*4);
        bf16x4v hv;
        hv[0]=(__bf16)w.x; hv[1]=(__bf16)w.y; hv[2]=(__bf16)w.z; hv[3]=(__bf16)w.w;
        *(bf16x4v*)((char*)uB + ((c*128 + q*8) ^ ((c&7)<<4))) = hv;
      }
      __syncthreads();
      bf16x8v bfr[2];
      #pragma unroll
      for (int kt=0; kt<2; ++kt){
        int cl = wv*16 + (lane&15);
        int byt = (cl*128 + kt*64 + (lane>>4)*16) ^ ((cl&7)<<4);
        bfr[kt] = *(const bf16x8v*)((const char*)uB + byt);
      }
      #pragma unroll
      for (int mt=0; mt<5; ++mt){
        bf16x8v afr[2];
        #pragma unroll
        for (int kt=0; kt<2; ++kt){
          int row = mt*16 + (lane&15);
          int byt = (row*128 + kt*64 + (lane>>4)*16) ^ ((row&7)<<4);
          afr[kt] = *(const bf16x8v*)((const char*)uA + byt);
        }
        acc[mt][p] = __builtin_amdgcn_mfma_f32_16x16x32_bf16(afr[0], bfr[0], acc[mt][p], 0,0,0);
        acc[mt][p] = __builtin_amdgcn_mfma_f32_16x16x32_bf16(afr[1], bfr[1], acc[mt][p], 0,0,0);
      }
      __syncthreads();
    }
  }

  // ---- P3/P4 by 32-row halves: xi -> uA (stride 132), z -> global (h=0),
  //      conv VECTORIZED: thread = (d-quad, 2 rows/half), float4 stores ----
  {
    const int d0w = wv*16 + (lane&15);          // fragment column (channel)
    const int dq = tid & 31, d0 = dq*4, rg = tid >> 5;
    float4 cwr[4];
    #pragma unroll
    for (int k=0;k<4;++k) cwr[k] = *(const float4*)(conv_w + (size_t)(i*DI + d0 + k)*KC);
    const float4 cb4 = *(const float4*)(conv_b + i*DI + d0);
    const float4 t0 = make_float4(cwr[0].x, cwr[1].x, cwr[2].x, cwr[3].x);
    const float4 t1 = make_float4(cwr[0].y, cwr[1].y, cwr[2].y, cwr[3].y);
    const float4 t2 = make_float4(cwr[0].z, cwr[1].z, cwr[2].z, cwr[3].z);
    const float4 t3 = make_float4(cwr[0].w, cwr[1].w, cwr[2].w, cwr[3].w);
    #pragma unroll
    for (int h=0; h<2; ++h) {
      #pragma unroll
      for (int mt=0; mt<5; ++mt)
        #pragma unroll
        for (int r=0; r<4; ++r){
          int m = mt*16 + (lane>>4)*4 + r;
          if (m >= h*32 && m <= h*32+34)
            uA[(m - h*32)*132 + d0w] = acc[mt][0][r];
        }
      if (h == 0) {
        #pragma unroll
        for (int mt=0; mt<5; ++mt)
          #pragma unroll
          for (int r=0; r<4; ++r){
            int m = mt*16 + (lane>>4)*4 + r;
            if (m >= 3 && m <= 66)
              zg[(rbase + (m-3))*DI + d0w] = acc[mt][1][r];
          }
      }
      __syncthreads();
      #pragma unroll
      for (int j=0; j<2; ++j){
        int lb = rg*2 + j;
        int r = h*32 + lb;
        float4 v0 = *(const float4*)&uA[(lb  )*132 + d0];
        float4 v1 = *(const float4*)&uA[(lb+1)*132 + d0];
        float4 v2 = *(const float4*)&uA[(lb+2)*132 + d0];
        float4 v3 = *(const float4*)&uA[(lb+3)*132 + d0];
        float4 aa;
        aa.x = cb4.x + t0.x*v0.x + t1.x*v1.x + t2.x*v2.x + t3.x*v3.x;
        aa.y = cb4.y + t0.y*v0.y + t1.y*v1.y + t2.y*v2.y + t3.y*v3.y;
        aa.z = cb4.z + t0.z*v0.z + t1.z*v1.z + t2.z*v2.z + t3.z*v3.z;
        aa.w = cb4.w + t0.w*v0.w + t1.w*v1.w + t2.w*v2.w + t3.w*v3.w;
        float4 xc4;
        xc4.x = aa.x * fsig(aa.x);
        xc4.y = aa.y * fsig(aa.y);
        xc4.z = aa.z * fsig(aa.z);
        xc4.w = aa.w * fsig(aa.w);
        *(float4*)&xcg[(rbase + r)*DI + d0] = xc4;
        bf16x4v hv;
        hv[0]=(__bf16)xc4.x; hv[1]=(__bf16)xc4.y; hv[2]=(__bf16)xc4.z; hv[3]=(__bf16)xc4.w;
        *(bf16x4v*)((char*)uB + ((r*256 + d0*2) ^ ((r&7)<<4))) = hv;
      }
      __syncthreads();
    }
  }

  // ---- P5: stage xp_w hi (0..9216B) + lo (9216..18432B) into uA ----
  for (int e = tid; e < 36*32; e += 512) {
    int j = e >> 5, k0 = (e & 31)*4;
    float4 w = *(const float4*)(xp_w + ((size_t)(i*36) + j)*DI + k0);
    float vv[4] = {w.x, w.y, w.z, w.w};
    bf16x4v hv, lv;
    #pragma unroll
    for (int k=0;k<4;++k){
      __bf16 hh = (__bf16)vv[k];
      hv[k] = hh;
      lv[k] = (__bf16)(vv[k] - (float)hh);
    }
    int off = (j*256 + k0*2) ^ ((j&7)<<4);
    *(bf16x4v*)((char*)uA + off) = hv;
    *(bf16x4v*)((char*)uA + off + 9216) = lv;
  }
  __syncthreads();

  // ---- P6: x_proj = xc_h*(w_h + w_l), 2 MFMAs; dtl->uA@4620, B/C->global ----
  for (int t = wv; t < 12; t += 8) {
    int mt = t & 3, nt = t >> 2;
    f32x4 a2 = {0.f,0.f,0.f,0.f};
    #pragma unroll
    for (int kt=0; kt<4; ++kt){
      int row = mt*16 + (lane&15);
      int ab = (row*256 + kt*64 + (lane>>4)*16) ^ ((row&7)<<4);
      bf16x8v ah = *(const bf16x8v*)((const char*)uB + ab);
      int col = nt*16 + (lane&15);
      int bby = (col*256 + kt*64 + (lane>>4)*16) ^ ((col&7)<<4);
      bf16x8v bh = *(const bf16x8v*)((const char*)uA + bby);
      bf16x8v bl = *(const bf16x8v*)((const char*)uA + bby + 9216);
      a2 = __builtin_amdgcn_mfma_f32_16x16x32_bf16(ah, bh, a2, 0,0,0);
      a2 = __builtin_amdgcn_mfma_f32_16x16x32_bf16(ah, bl, a2, 0,0,0);
    }
    #pragma unroll
    for (int rg4=0; rg4<4; ++rg4){
      int row = mt*16 + (lane>>4)*4 + rg4;
      int j = nt*16 + (lane&15);
      float val = a2[rg4];
      if (j < 4) uA[4620 + row*4 + j] = val;
      else if (j < 20) Bg[(rbase+row)*NS + (j-4)] = val;
      else if (j < 36) Cg[(rbase+row)*NS + (j-20)] = val;
    }
  }
  __syncthreads();

  // ---- P7: dt = softplus, VECTORIZED (4 d per thread, float4 store) ----
  #pragma unroll
  for (int it=0; it<4; ++it) {
    int e = it*512 + tid;
    int r = e >> 5, dq = e & 31, d0 = dq*4;
    float4 dl = *(const float4*)&uA[4620 + r*4];
    float4 bb = *(const float4*)(dt_b + i*DI + d0);
    float4 o;
    #pragma unroll
    for (int k=0;k<4;++k){
      float4 w = *(const float4*)(dtp_w + (size_t)(i*DI + d0 + k)*RK);
      float a = ((const float*)&bb)[k] + dot4(w, dl);
      ((float*)&o)[k] = (a > 15.f) ? a : __logf(1.f + __expf(a));
    }
    *(float4*)&dtg[(rbase + r)*DI + d0] = o;
  }
}

// ---------------------------------------------------------------------------
// KS v2 (round-16 proven): local scan, B/C in LDS + dt/x double-buffer.
// ---------------------------------------------------------------------------
__global__ __launch_bounds__(256) void ks_scan(
    float* dtg, float* xcg,
    const float* __restrict__ Bg, const float* __restrict__ Cg,
    const float* __restrict__ A_log, const float* __restrict__ Dp,
    float* __restrict__ Pm, float* __restrict__ hend)
{
  __shared__ float sB[CT*NS];
  __shared__ float sC[CT*NS];
  const int tid = threadIdx.x;
  const int bx = blockIdx.x;
  const int c = bx % NC; const int i = (bx/NC)&1; const int b = bx/(2*NC);
  const int d = tid >> 1, half = tid & 1, n0 = half*8;
  const size_t rb = ((size_t)(b*2+i)*Lx + (size_t)c*CT);
  ((float4*)sB)[tid] = ((const float4*)(Bg + rb*NS))[tid];
  ((float4*)sC)[tid] = ((const float4*)(Cg + rb*NS))[tid];
  float a[8], h[8];
  bool afast = true;
  #pragma unroll
  for (int n=0;n<8;++n){
    a[n] = -__expf(A_log[((size_t)(i*DI)+d)*NS + n0+n]);
    float tgt = (float)(n0+n+1);
    afast = afast && (fabsf(a[n] + tgt) <= 1e-4f*tgt);
    h[n] = 0.f;
  }
  const float Dd = Dp[i*DI + d];
  float S = 0.f;
  float dt4[4], x4[4];
  #pragma unroll
  for (int k=0;k<4;++k){
    size_t g = (rb + k)*DI + d;
    dt4[k] = dtg[g];
    x4[k]  = xcg[g];
  }
  __syncthreads();
  for (int r4 = 0; r4 < CT; r4 += 4){
    float dtn[4], xn[4];
    if (r4 + 4 < CT){
      #pragma unroll
      for (int k=0;k<4;++k){
        size_t g = (rb + r4 + 4 + k)*DI + d;
        dtn[k] = dtg[g];
        xn[k]  = xcg[g];
      }
    }
    #pragma unroll
    for (int k=0;k<4;++k){
      float dtt = dt4[k];
      float xcv = x4[k];
      float u = dtt * xcv;
      S += dtt;
      const float* bp = &sB[(r4 + k)*NS + n0];
      const float* cp = &sC[(r4 + k)*NS + n0];
      float4 b0 = *(const float4*)bp;
      float4 b1 = *(const float4*)(bp+4);
      float4 c0 = *(const float4*)cp;
      float4 c1 = *(const float4*)(cp+4);
      float bb[8] = {b0.x,b0.y,b0.z,b0.w,b1.x,b1.y,b1.z,b1.w};
      float cc[8] = {c0.x,c0.y,c0.z,c0.w,c1.x,c1.y,c1.z,c1.w};
      float pA = 0.f, pB = 0.f;
      if (afast){
        float p[8];
        pow8(__expf(-dtt), half, p);
        #pragma unroll
        for (int n=0;n<8;++n){
          h[n] = fmaf(p[n], h[n], u*bb[n]);
          if (n & 1) pB = fmaf(h[n], cc[n], pB); else pA = fmaf(h[n], cc[n], pA);
        }
      } else {
        #pragma unroll
        for (int n=0;n<8;++n){
          float dA = __expf(a[n]*dtt);
          h[n] = fmaf(dA, h[n], u*bb[n]);
          if (n & 1) pB = fmaf(h[n], cc[n], pB); else pA = fmaf(h[n], cc[n], pA);
        }
      }
      float part = pA + pB;
      float y = part + __shfl_xor(part, 1);
      if (half == 0){
        size_t g = (rb + r4 + k)*DI + d;
        dtg[g] = fmaf(xcv, Dd, y);
        xcg[g] = S;
      }
    }
    if (r4 + 4 < CT){
      #pragma unroll
      for (int k=0;k<4;++k){ dt4[k] = dtn[k]; x4[k] = xn[k]; }
    }
  }
  size_t ob = (((size_t)(b*2+i)*NC + c)*DI + d)*NS + n0;
  if (afast){
    float p[8];
    pow8(__expf(-S), half, p);
    #pragma unroll
    for (int n=0;n<8;++n) Pm[ob+n] = p[n];
  } else {
    #pragma unroll
    for (int n=0;n<8;++n) Pm[ob+n] = __expf(a[n]*S);
  }
  #pragma unroll
  for (int n=0;n<8;++n) hend[ob+n] = h[n];
}

// ---------------------------------------------------------------------------
// KC v2: chunk propagation with prefetch (in-place h0 over Pm)
// ---------------------------------------------------------------------------
__global__ __launch_bounds__(256) void kc_pass2(
    float* __restrict__ Pm, const float* __restrict__ hend)
{
  const int tid = threadIdx.x;
  const int bi = blockIdx.x;
  const int d = tid>>1, n0 = (tid&1)*8;
  float h[8];
  #pragma unroll
  for (int n=0;n<8;++n) h[n]=0.f;
  const size_t stride = (size_t)DI*NS;
  size_t ob = (((size_t)bi*NC)*DI + d)*NS + n0;
  float4 pa = *(const float4*)&Pm[ob],   pb = *(const float4*)&Pm[ob+4];
  float4 ea = *(const float4*)&hend[ob], eb = *(const float4*)&hend[ob+4];
  for (int c=0; c<NC; ++c){
    size_t obn = ob + stride;
    float4 qa=pa, qb=pb, fa=ea, fb=eb;
    if (c+1 < NC){
      qa = *(const float4*)&Pm[obn];   qb = *(const float4*)&Pm[obn+4];
      fa = *(const float4*)&hend[obn]; fb = *(const float4*)&hend[obn+4];
    }
    *(float4*)&Pm[ob]   = make_float4(h[0],h[1],h[2],h[3]);
    *(float4*)&Pm[ob+4] = make_float4(h[4],h[5],h[6],h[7]);
    h[0]=fmaf(pa.x,h[0],ea.x); h[1]=fmaf(pa.y,h[1],ea.y);
    h[2]=fmaf(pa.z,h[2],ea.z); h[3]=fmaf(pa.w,h[3],ea.w);
    h[4]=fmaf(pb.x,h[4],eb.x); h[5]=fmaf(pb.y,h[5],eb.y);
    h[6]=fmaf(pb.z,h[6],eb.z); h[7]=fmaf(pb.w,h[7],eb.w);
    pa=qa; pb=qb; ea=fa; eb=fb; ob = obn;
  }
}

// ---------------------------------------------------------------------------
// KE v8 (round-22 proven): 32-row tiles + h0 staged in LDS (coalesced),
// Horner correction + gate fused into Y staging, bf16 MFMA out-proj.
// ---------------------------------------------------------------------------
__global__ __launch_bounds__(256) void ke_out(
    const float* __restrict__ yg, const float* __restrict__ Sg,
    const float* __restrict__ zg, const float* __restrict__ Cg,
    const float* __restrict__ h0g, const float* __restrict__ A_log,
    const float* __restrict__ ow, float* __restrict__ out)
{
  __shared__ char sY[16384];
  __shared__ char sW[16384];
  __shared__ float sH[2*128*17];
  __shared__ int s_af[2];
  const int tid = threadIdx.x;
  const int bx = blockIdx.x;
  const int tile = bx & 127; const int b = bx >> 7;
  const int l0 = tile * 32;
  const int q = tid & 31, rg = tid >> 5;
  if (tid < 2) s_af[tid] = 1;
  bool bad0 = false, bad1 = false;
  #pragma unroll
  for (int it=0; it<8; ++it){
    int e = it*256 + tid;
    int n = e & 15;
    float tgt = (float)(n+1);
    float a0 = __expf(A_log[e]);
    float a1 = __expf(A_log[DI*NS + e]);
    if (fabsf(a0 - tgt) > 1e-4f*tgt) bad0 = true;
    if (fabsf(a1 - tgt) > 1e-4f*tgt) bad1 = true;
  }
  {
    const int cch0 = (l0 >> 6), cch1 = ((Lx-1-l0) >> 6);
    #pragma unroll
    for (int it=0; it<4; ++it){
      int f = it*256 + tid;
      int dir = f >> 9, rem = f & 511;
      int dd = rem >> 2, k = rem & 3;
      size_t strm = (size_t)(b*2+dir);
      int cch = dir ? cch1 : cch0;
      float4 v = *(const float4*)&h0g[(((strm*NC)+cch)*DI + dd)*NS + k*4];
      float* hp = &sH[dir*2176 + dd*17 + k*4];
      hp[0]=v.x; hp[1]=v.y; hp[2]=v.z; hp[3]=v.w;
    }
  }
  __syncthreads();
  if (bad0) s_af[0] = 0;
  if (bad1) s_af[1] = 0;
  __syncthreads();
  const bool af0 = (s_af[0] != 0), af1 = (s_af[1] != 0);
  #pragma unroll
  for (int dir=0; dir<2; ++dir){
    const size_t strm = (size_t)(b*2+dir);
    const bool afast = dir ? af1 : af0;
    float h0q[4][16];
    #pragma unroll
    for (int dd=0; dd<4; ++dd){
      const float* hp = &sH[dir*2176 + (q*4+dd)*17];
      #pragma unroll
      for (int n=0;n<16;++n) h0q[dd][n] = hp[n];
    }
    #pragma unroll
    for (int it=0; it<4; ++it){
      int r = it*8 + rg;
      size_t prow = strm*Lx + (size_t)(dir ? (Lx-1-(l0+r)) : (l0+r));
      float4 y4 = *(const float4*)&yg[prow*DI + q*4];
      float4 S4 = *(const float4*)&Sg[prow*DI + q*4];
      float4 z4 = *(const float4*)&zg[prow*DI + q*4];
      float c16[16];
      #pragma unroll
      for (int k=0;k<4;++k) *(float4*)&c16[k*4] = *(const float4*)&Cg[prow*NS + k*4];
      float yv[4] = {y4.x,y4.y,y4.z,y4.w};
      float Sv[4] = {S4.x,S4.y,S4.z,S4.w};
      float zv[4] = {z4.x,z4.y,z4.z,z4.w};
      bf16x4v hv;
      #pragma unroll
      for (int dd=0; dd<4; ++dd){
        float corr;
        if (afast){
          float e1 = __expf(-Sv[dd]);
          float g[16];
          #pragma unroll
          for (int n=0;n<16;++n) g[n] = c16[n]*h0q[dd][n];
          float t = g[15];
          #pragma unroll
          for (int n=14;n>=0;--n) t = fmaf(t, e1, g[n]);
          corr = t * e1;
        } else {
          corr = 0.f;
          #pragma unroll
          for (int n=0;n<16;++n){
            float an = -__expf(A_log[((size_t)(dir*DI) + q*4+dd)*NS + n]);
            corr = fmaf(__expf(an*Sv[dd])*c16[n], h0q[dd][n], corr);
          }
        }
        float zz = zv[dd];
        float yf = (yv[dd] + corr) * (zz * fsig(zz));
        hv[dd] = (__bf16)yf;
      }
      *(bf16x4v*)(sY + ((r*512 + dir*256 + q*8) ^ ((r&7)<<4))) = hv;
    }
  }
  __syncthreads();
  const int lane = tid & 63, wv = tid >> 6;
  f32x4 acc2[2] = {{0.f,0.f,0.f,0.f},{0.f,0.f,0.f,0.f}};
  #pragma unroll
  for (int dir=0; dir<2; ++dir){
    #pragma unroll
    for (int it=0; it<8; ++it){
      int e = it*256 + tid;
      int c = e >> 5, qq = e & 31;
      float4 w = *(const float4*)(ow + ((size_t)(dir*DM + c))*DI + qq*4);
      bf16x4v hv; hv[0]=(__bf16)w.x; hv[1]=(__bf16)w.y; hv[2]=(__bf16)w.z; hv[3]=(__bf16)w.w;
      *(bf16x4v*)(sW + ((c*256 + qq*8) ^ ((c&7)<<4))) = hv;
    }
    __syncthreads();
    #pragma unroll
    for (int t=0; t<2; ++t){
      int T = wv*2 + t, mt = T >> 2, nt = T & 3;
      #pragma unroll
      for (int ktl=0; ktl<4; ++ktl){
        int row = mt*16 + (lane&15);
        bf16x8v av = *(const bf16x8v*)(sY + ((row*512 + dir*256 + ktl*64 + (lane>>4)*16) ^ ((row&7)<<4)));
        int ch = nt*16 + (lane&15);
        bf16x8v wvv = *(const bf16x8v*)(sW + ((ch*256 + ktl*64 + (lane>>4)*16) ^ ((ch&7)<<4)));
        acc2[t] = __builtin_amdgcn_mfma_f32_16x16x32_bf16(av, wvv, acc2[t], 0,0,0);
      }
    }
    __syncthreads();
  }
  #pragma unroll
  for (int t=0; t<2; ++t){
    int T = wv*2 + t, mt = T >> 2, nt = T & 3;
    #pragma unroll
    for (int r=0; r<4; ++r){
      int m = mt*16 + (lane>>4)*4 + r;
      int ch = nt*16 + (lane&15);
      out[((size_t)b*Lx + (size_t)(l0+m))*DM + ch] = acc2[t][r];
    }
  }
}

extern "C" void kernel_launch(void* const* d_in, const int* in_sizes, int n_in,
                              void* d_out, int out_size, void* d_ws, size_t ws_size,
                              hipStream_t stream)
{
  const float* x      = (const float*)d_in[0];
  const float* ln_g   = (const float*)d_in[1];
  const float* ln_b   = (const float*)d_in[2];
  const float* in_w   = (const float*)d_in[3];
  const float* conv_w = (const float*)d_in[4];
  const float* conv_b = (const float*)d_in[5];
  const float* xp_w   = (const float*)d_in[6];
  const float* dtp_w  = (const float*)d_in[7];
  const float* dt_b   = (const float*)d_in[8];
  const float* A_log  = (const float*)d_in[9];
  const float* Dp     = (const float*)d_in[10];
  const float* ow     = (const float*)d_in[11];
  float* out = (float*)d_out;
  float* ws = (float*)d_ws;
  const size_t NBD = (size_t)Bsz*2*Lx*DI;     // 8,388,608
  const size_t NBN = (size_t)Bsz*2*Lx*NS;     // 1,048,576
  float* xcg = ws;                 // xc -> S (in place, ks_scan)
  float* dtg = xcg + NBD;          // dt -> y_local (in place, ks_scan)
  float* zg  = dtg + NBD;
  float* Bg  = zg + NBD;
  float* Cg  = Bg + NBN;
  float* Pm  = Cg + NBN;           // chunk P; becomes h0 in-place after kc
  float* he  = out;                // hend staged in d_out (overwritten by ke)

  a1_front<<<dim3(Bsz*2*(Lx/64)), dim3(512), 0, stream>>>(
      x, ln_g, ln_b, in_w, conv_w, conv_b, xp_w, dtp_w, dt_b, xcg, dtg, zg, Bg, Cg);
  ks_scan<<<dim3(Bsz*2*NC), dim3(256), 0, stream>>>(dtg, xcg, Bg, Cg, A_log, Dp, Pm, he);
  kc_pass2<<<dim3(Bsz*2), dim3(256), 0, stream>>>(Pm, he);
  ke_out<<<dim3(Bsz*(Lx/32)), dim3(256), 0, stream>>>(
      dtg, xcg, zg, Cg, Pm, A_log, ow, out);
}

// Round 24
// 124.634 us; speedup vs baseline: 1.0011x; 1.0011x over previous
//
#include <hip/hip_runtime.h>

#define Bsz 8
#define Lx 4096
#define DM 64
#define DI 128
#define NS 16
#define RK 4
#define KC 4
#define NC 64
#define CT 64

typedef __attribute__((ext_vector_type(8))) __bf16 bf16x8v;
typedef __attribute__((ext_vector_type(4))) __bf16 bf16x4v;
typedef __attribute__((ext_vector_type(4))) float f32x4;

__device__ __forceinline__ float fsig(float x){ return 1.f/(1.f+__expf(-x)); }
__device__ __forceinline__ float dot4(float4 a, float4 b){
  return fmaf(a.x,b.x, fmaf(a.y,b.y, fmaf(a.z,b.z, a.w*b.w)));
}
// powers e1^(n0+1)..e1^(n0+8), log-depth
__device__ __forceinline__ void pow8(float e1, int half, float p[8]){
  float e2=e1*e1, e4=e2*e2, e8=e4*e4;
  if (half){
    p[0]=e8*e1; p[1]=e8*e2; p[2]=p[1]*e1; p[3]=e8*e4;
    p[4]=p[3]*e1; p[5]=p[3]*e2; p[6]=p[5]*e1; p[7]=e8*e8;
  } else {
    p[0]=e1; p[1]=e2; p[2]=e2*e1; p[3]=e4;
    p[4]=e4*e1; p[5]=e4*e2; p[6]=p[5]*e1; p[7]=e8;
  }
}

// ---------------------------------------------------------------------------
// A1 v12 (round-20/22 proven): 2-half W staging, xc-hi x_proj, coalesced writes.
// ---------------------------------------------------------------------------
__global__ __launch_bounds__(512) void a1_front(
    const float* __restrict__ x, const float* __restrict__ ln_g, const float* __restrict__ ln_b,
    const float* __restrict__ in_w, const float* __restrict__ conv_w, const float* __restrict__ conv_b,
    const float* __restrict__ xp_w, const float* __restrict__ dtp_w, const float* __restrict__ dt_b,
    float* __restrict__ xcg, float* __restrict__ dtg, float* __restrict__ zg,
    float* __restrict__ Bg, float* __restrict__ Cg)
{
  __shared__ float uA[4864];
  __shared__ float uB[4096];
  const int tid = threadIdx.x;
  const int bx = blockIdx.x;
  const int tile = bx & 63;
  const int i = (bx >> 6) & 1;
  const int b = bx >> 7;
  const int l0 = tile * 64;
  const size_t rbase = (size_t)(b*2+i)*Lx + l0;
  const int lane = tid & 63, wv = tid >> 6;

  {
    const float gg = ln_g[lane], bb = ln_b[lane];
    for (int lr = wv; lr < 67; lr += 8) {
      float v = 0.f;
      int l = l0 - 3 + lr;
      if (l >= 0) {
        int pl = i ? (Lx-1-l) : l;
        v = x[((size_t)b*Lx + pl)*DM + lane];
        float s = v, s2 = v*v;
        #pragma unroll
        for (int off=32; off; off>>=1){ s += __shfl_xor(s,off); s2 += __shfl_xor(s2,off); }
        float mu = s * (1.f/DM);
        float rs = rsqrtf(s2*(1.f/DM) - mu*mu + 1e-5f);
        v = (v-mu)*rs*gg + bb;
      }
      *(__bf16*)((char*)uA + ((lr*128 + lane*2) ^ ((lr&7)<<4))) = (__bf16)v;
    }
  }
  __syncthreads();

  f32x4 acc[5][2];
  {
    f32x4 z4v = {0.f, 0.f, 0.f, 0.f};
    #pragma unroll
    for (int mt=0; mt<5; ++mt){ acc[mt][0] = z4v; acc[mt][1] = z4v; }
    #pragma unroll
    for (int p = 0; p < 2; ++p) {
      #pragma unroll
      for (int it=0; it<4; ++it) {
        int g = it*512 + tid;
        int c = g >> 4, q = g & 15;
        float4 w = *(const float4*)(in_w + ((size_t)(i*2*DI) + p*DI + c)*DM + q*4);
        bf16x4v hv;
        hv[0]=(__bf16)w.x; hv[1]=(__bf16)w.y; hv[2]=(__bf16)w.z; hv[3]=(__bf16)w.w;
        *(bf16x4v*)((char*)uB + ((c*128 + q*8) ^ ((c&7)<<4))) = hv;
      }
      __syncthreads();
      bf16x8v bfr[2];
      #pragma unroll
      for (int kt=0; kt<2; ++kt){
        int cl = wv*16 + (lane&15);
        int byt = (cl*128 + kt*64 + (lane>>4)*16) ^ ((cl&7)<<4);
        bfr[kt] = *(const bf16x8v*)((const char*)uB + byt);
      }
      #pragma unroll
      for (int mt=0; mt<5; ++mt){
        bf16x8v afr[2];
        #pragma unroll
        for (int kt=0; kt<2; ++kt){
          int row = mt*16 + (lane&15);
          int byt = (row*128 + kt*64 + (lane>>4)*16) ^ ((row&7)<<4);
          afr[kt] = *(const bf16x8v*)((const char*)uA + byt);
        }
        acc[mt][p] = __builtin_amdgcn_mfma_f32_16x16x32_bf16(afr[0], bfr[0], acc[mt][p], 0,0,0);
        acc[mt][p] = __builtin_amdgcn_mfma_f32_16x16x32_bf16(afr[1], bfr[1], acc[mt][p], 0,0,0);
      }
      __syncthreads();
    }
  }

  {
    const int d0 = wv*16 + (lane&15);
    const int d = tid & 127, rh = tid >> 7;
    const float4 cw = *(const float4*)(conv_w + (size_t)(i*DI + d)*KC);
    const float cb = conv_b[i*DI + d];
    #pragma unroll
    for (int h=0; h<2; ++h) {
      #pragma unroll
      for (int mt=0; mt<5; ++mt)
        #pragma unroll
        for (int r=0; r<4; ++r){
          int m = mt*16 + (lane>>4)*4 + r;
          if (m >= h*32 && m <= h*32+34)
            uA[(m - h*32)*129 + d0] = acc[mt][0][r];
        }
      if (h == 0) {
        #pragma unroll
        for (int mt=0; mt<5; ++mt)
          #pragma unroll
          for (int r=0; r<4; ++r){
            int m = mt*16 + (lane>>4)*4 + r;
            if (m >= 3 && m <= 66)
              zg[(rbase + (m-3))*DI + d0] = acc[mt][1][r];
          }
      }
      __syncthreads();
      #pragma unroll
      for (int rr=0; rr<8; ++rr){
        int lb = rh*8 + rr;
        int r = h*32 + lb;
        float v0 = uA[(lb  )*129 + d];
        float v1 = uA[(lb+1)*129 + d];
        float v2 = uA[(lb+2)*129 + d];
        float v3 = uA[(lb+3)*129 + d];
        float aa = cb + cw.x*v0 + cw.y*v1 + cw.z*v2 + cw.w*v3;
        float xc = aa * fsig(aa);
        xcg[(rbase + r)*DI + d] = xc;
        int off = (r*256 + d*2) ^ ((r&7)<<4);
        *(__bf16*)((char*)uB + off) = (__bf16)xc;
      }
      __syncthreads();
    }
  }

  for (int e = tid; e < 36*32; e += 512) {
    int j = e >> 5, k0 = (e & 31)*4;
    float4 w = *(const float4*)(xp_w + ((size_t)(i*36) + j)*DI + k0);
    float vv[4] = {w.x, w.y, w.z, w.w};
    bf16x4v hv, lv;
    #pragma unroll
    for (int k=0;k<4;++k){
      __bf16 hh = (__bf16)vv[k];
      hv[k] = hh;
      lv[k] = (__bf16)(vv[k] - (float)hh);
    }
    int off = (j*256 + k0*2) ^ ((j&7)<<4);
    *(bf16x4v*)((char*)uA + off) = hv;
    *(bf16x4v*)((char*)uA + off + 9216) = lv;
  }
  __syncthreads();

  for (int t = wv; t < 12; t += 8) {
    int mt = t & 3, nt = t >> 2;
    f32x4 a2 = {0.f,0.f,0.f,0.f};
    #pragma unroll
    for (int kt=0; kt<4; ++kt){
      int row = mt*16 + (lane&15);
      int ab = (row*256 + kt*64 + (lane>>4)*16) ^ ((row&7)<<4);
      bf16x8v ah = *(const bf16x8v*)((const char*)uB + ab);
      int col = nt*16 + (lane&15);
      int bby = (col*256 + kt*64 + (lane>>4)*16) ^ ((col&7)<<4);
      bf16x8v bh = *(const bf16x8v*)((const char*)uA + bby);
      bf16x8v bl = *(const bf16x8v*)((const char*)uA + bby + 9216);
      a2 = __builtin_amdgcn_mfma_f32_16x16x32_bf16(ah, bh, a2, 0,0,0);
      a2 = __builtin_amdgcn_mfma_f32_16x16x32_bf16(ah, bl, a2, 0,0,0);
    }
    #pragma unroll
    for (int rg4=0; rg4<4; ++rg4){
      int row = mt*16 + (lane>>4)*4 + rg4;
      int j = nt*16 + (lane&15);
      float val = a2[rg4];
      if (j < 4) uA[4608 + row*4 + j] = val;
      else if (j < 20) Bg[(rbase+row)*NS + (j-4)] = val;
      else if (j < 36) Cg[(rbase+row)*NS + (j-20)] = val;
    }
  }
  __syncthreads();

  #pragma unroll 4
  for (int it=0; it<16; ++it) {
    int e = it*512 + tid;
    int r = e >> 7, d = e & 127;
    float4 dl = *(const float4*)&uA[4608 + r*4];
    float4 w  = *(const float4*)(dtp_w + (size_t)(i*DI + d)*RK);
    float a = dt_b[i*DI + d] + dot4(w, dl);
    dtg[(rbase + r)*DI + d] = (a > 15.f) ? a : __logf(1.f + __expf(a));
  }
}

// ---------------------------------------------------------------------------
// KS v2 (round-16 proven): local scan, B/C in LDS + dt/x double-buffer.
// ---------------------------------------------------------------------------
__global__ __launch_bounds__(256) void ks_scan(
    float* dtg, float* xcg,
    const float* __restrict__ Bg, const float* __restrict__ Cg,
    const float* __restrict__ A_log, const float* __restrict__ Dp,
    float* __restrict__ Pm, float* __restrict__ hend)
{
  __shared__ float sB[CT*NS];
  __shared__ float sC[CT*NS];
  const int tid = threadIdx.x;
  const int bx = blockIdx.x;
  const int c = bx % NC; const int i = (bx/NC)&1; const int b = bx/(2*NC);
  const int d = tid >> 1, half = tid & 1, n0 = half*8;
  const size_t rb = ((size_t)(b*2+i)*Lx + (size_t)c*CT);
  ((float4*)sB)[tid] = ((const float4*)(Bg + rb*NS))[tid];
  ((float4*)sC)[tid] = ((const float4*)(Cg + rb*NS))[tid];
  float a[8], h[8];
  bool afast = true;
  #pragma unroll
  for (int n=0;n<8;++n){
    a[n] = -__expf(A_log[((size_t)(i*DI)+d)*NS + n0+n]);
    float tgt = (float)(n0+n+1);
    afast = afast && (fabsf(a[n] + tgt) <= 1e-4f*tgt);
    h[n] = 0.f;
  }
  const float Dd = Dp[i*DI + d];
  float S = 0.f;
  float dt4[4], x4[4];
  #pragma unroll
  for (int k=0;k<4;++k){
    size_t g = (rb + k)*DI + d;
    dt4[k] = dtg[g];
    x4[k]  = xcg[g];
  }
  __syncthreads();
  for (int r4 = 0; r4 < CT; r4 += 4){
    float dtn[4], xn[4];
    if (r4 + 4 < CT){
      #pragma unroll
      for (int k=0;k<4;++k){
        size_t g = (rb + r4 + 4 + k)*DI + d;
        dtn[k] = dtg[g];
        xn[k]  = xcg[g];
      }
    }
    #pragma unroll
    for (int k=0;k<4;++k){
      float dtt = dt4[k];
      float xcv = x4[k];
      float u = dtt * xcv;
      S += dtt;
      const float* bp = &sB[(r4 + k)*NS + n0];
      const float* cp = &sC[(r4 + k)*NS + n0];
      float4 b0 = *(const float4*)bp;
      float4 b1 = *(const float4*)(bp+4);
      float4 c0 = *(const float4*)cp;
      float4 c1 = *(const float4*)(cp+4);
      float bb[8] = {b0.x,b0.y,b0.z,b0.w,b1.x,b1.y,b1.z,b1.w};
      float cc[8] = {c0.x,c0.y,c0.z,c0.w,c1.x,c1.y,c1.z,c1.w};
      float pA = 0.f, pB = 0.f;
      if (afast){
        float p[8];
        pow8(__expf(-dtt), half, p);
        #pragma unroll
        for (int n=0;n<8;++n){
          h[n] = fmaf(p[n], h[n], u*bb[n]);
          if (n & 1) pB = fmaf(h[n], cc[n], pB); else pA = fmaf(h[n], cc[n], pA);
        }
      } else {
        #pragma unroll
        for (int n=0;n<8;++n){
          float dA = __expf(a[n]*dtt);
          h[n] = fmaf(dA, h[n], u*bb[n]);
          if (n & 1) pB = fmaf(h[n], cc[n], pB); else pA = fmaf(h[n], cc[n], pA);
        }
      }
      float part = pA + pB;
      float y = part + __shfl_xor(part, 1);
      if (half == 0){
        size_t g = (rb + r4 + k)*DI + d;
        dtg[g] = fmaf(xcv, Dd, y);
        xcg[g] = S;
      }
    }
    if (r4 + 4 < CT){
      #pragma unroll
      for (int k=0;k<4;++k){ dt4[k] = dtn[k]; x4[k] = xn[k]; }
    }
  }
  size_t ob = (((size_t)(b*2+i)*NC + c)*DI + d)*NS + n0;
  if (afast){
    float p[8];
    pow8(__expf(-S), half, p);
    #pragma unroll
    for (int n=0;n<8;++n) Pm[ob+n] = p[n];
  } else {
    #pragma unroll
    for (int n=0;n<8;++n) Pm[ob+n] = __expf(a[n]*S);
  }
  #pragma unroll
  for (int n=0;n<8;++n) hend[ob+n] = h[n];
}

// ---------------------------------------------------------------------------
// KC v2: chunk propagation with prefetch (in-place h0 over Pm)
// ---------------------------------------------------------------------------
__global__ __launch_bounds__(256) void kc_pass2(
    float* __restrict__ Pm, const float* __restrict__ hend)
{
  const int tid = threadIdx.x;
  const int bi = blockIdx.x;
  const int d = tid>>1, n0 = (tid&1)*8;
  float h[8];
  #pragma unroll
  for (int n=0;n<8;++n) h[n]=0.f;
  const size_t stride = (size_t)DI*NS;
  size_t ob = (((size_t)bi*NC)*DI + d)*NS + n0;
  float4 pa = *(const float4*)&Pm[ob],   pb = *(const float4*)&Pm[ob+4];
  float4 ea = *(const float4*)&hend[ob], eb = *(const float4*)&hend[ob+4];
  for (int c=0; c<NC; ++c){
    size_t obn = ob + stride;
    float4 qa=pa, qb=pb, fa=ea, fb=eb;
    if (c+1 < NC){
      qa = *(const float4*)&Pm[obn];   qb = *(const float4*)&Pm[obn+4];
      fa = *(const float4*)&hend[obn]; fb = *(const float4*)&hend[obn+4];
    }
    *(float4*)&Pm[ob]   = make_float4(h[0],h[1],h[2],h[3]);
    *(float4*)&Pm[ob+4] = make_float4(h[4],h[5],h[6],h[7]);
    h[0]=fmaf(pa.x,h[0],ea.x); h[1]=fmaf(pa.y,h[1],ea.y);
    h[2]=fmaf(pa.z,h[2],ea.z); h[3]=fmaf(pa.w,h[3],ea.w);
    h[4]=fmaf(pb.x,h[4],eb.x); h[5]=fmaf(pb.y,h[5],eb.y);
    h[6]=fmaf(pb.z,h[6],eb.z); h[7]=fmaf(pb.w,h[7],eb.w);
    pa=qa; pb=qb; ea=fa; eb=fb; ob = obn;
  }
}

// ---------------------------------------------------------------------------
// KE v8 (round-22 proven): 32-row tiles + h0 staged in LDS (coalesced),
// Horner correction + gate fused into Y staging, bf16 MFMA out-proj.
// ---------------------------------------------------------------------------
__global__ __launch_bounds__(256) void ke_out(
    const float* __restrict__ yg, const float* __restrict__ Sg,
    const float* __restrict__ zg, const float* __restrict__ Cg,
    const float* __restrict__ h0g, const float* __restrict__ A_log,
    const float* __restrict__ ow, float* __restrict__ out)
{
  __shared__ char sY[16384];
  __shared__ char sW[16384];
  __shared__ float sH[2*128*17];
  __shared__ int s_af[2];
  const int tid = threadIdx.x;
  const int bx = blockIdx.x;
  const int tile = bx & 127; const int b = bx >> 7;
  const int l0 = tile * 32;
  const int q = tid & 31, rg = tid >> 5;
  if (tid < 2) s_af[tid] = 1;
  bool bad0 = false, bad1 = false;
  #pragma unroll
  for (int it=0; it<8; ++it){
    int e = it*256 + tid;
    int n = e & 15;
    float tgt = (float)(n+1);
    float a0 = __expf(A_log[e]);
    float a1 = __expf(A_log[DI*NS + e]);
    if (fabsf(a0 - tgt) > 1e-4f*tgt) bad0 = true;
    if (fabsf(a1 - tgt) > 1e-4f*tgt) bad1 = true;
  }
  {
    const int cch0 = (l0 >> 6), cch1 = ((Lx-1-l0) >> 6);
    #pragma unroll
    for (int it=0; it<4; ++it){
      int f = it*256 + tid;
      int dir = f >> 9, rem = f & 511;
      int dd = rem >> 2, k = rem & 3;
      size_t strm = (size_t)(b*2+dir);
      int cch = dir ? cch1 : cch0;
      float4 v = *(const float4*)&h0g[(((strm*NC)+cch)*DI + dd)*NS + k*4];
      float* hp = &sH[dir*2176 + dd*17 + k*4];
      hp[0]=v.x; hp[1]=v.y; hp[2]=v.z; hp[3]=v.w;
    }
  }
  __syncthreads();
  if (bad0) s_af[0] = 0;
  if (bad1) s_af[1] = 0;
  __syncthreads();
  const bool af0 = (s_af[0] != 0), af1 = (s_af[1] != 0);
  #pragma unroll
  for (int dir=0; dir<2; ++dir){
    const size_t strm = (size_t)(b*2+dir);
    const bool afast = dir ? af1 : af0;
    float h0q[4][16];
    #pragma unroll
    for (int dd=0; dd<4; ++dd){
      const float* hp = &sH[dir*2176 + (q*4+dd)*17];
      #pragma unroll
      for (int n=0;n<16;++n) h0q[dd][n] = hp[n];
    }
    #pragma unroll
    for (int it=0; it<4; ++it){
      int r = it*8 + rg;
      size_t prow = strm*Lx + (size_t)(dir ? (Lx-1-(l0+r)) : (l0+r));
      float4 y4 = *(const float4*)&yg[prow*DI + q*4];
      float4 S4 = *(const float4*)&Sg[prow*DI + q*4];
      float4 z4 = *(const float4*)&zg[prow*DI + q*4];
      float c16[16];
      #pragma unroll
      for (int k=0;k<4;++k) *(float4*)&c16[k*4] = *(const float4*)&Cg[prow*NS + k*4];
      float yv[4] = {y4.x,y4.y,y4.z,y4.w};
      float Sv[4] = {S4.x,S4.y,S4.z,S4.w};
      float zv[4] = {z4.x,z4.y,z4.z,z4.w};
      bf16x4v hv;
      #pragma unroll
      for (int dd=0; dd<4; ++dd){
        float corr;
        if (afast){
          float e1 = __expf(-Sv[dd]);
          float g[16];
          #pragma unroll
          for (int n=0;n<16;++n) g[n] = c16[n]*h0q[dd][n];
          float t = g[15];
          #pragma unroll
          for (int n=14;n>=0;--n) t = fmaf(t, e1, g[n]);
          corr = t * e1;
        } else {
          corr = 0.f;
          #pragma unroll
          for (int n=0;n<16;++n){
            float an = -__expf(A_log[((size_t)(dir*DI) + q*4+dd)*NS + n]);
            corr = fmaf(__expf(an*Sv[dd])*c16[n], h0q[dd][n], corr);
          }
        }
        float zz = zv[dd];
        float yf = (yv[dd] + corr) * (zz * fsig(zz));
        hv[dd] = (__bf16)yf;
      }
      *(bf16x4v*)(sY + ((r*512 + dir*256 + q*8) ^ ((r&7)<<4))) = hv;
    }
  }
  __syncthreads();
  const int lane = tid & 63, wv = tid >> 6;
  f32x4 acc2[2] = {{0.f,0.f,0.f,0.f},{0.f,0.f,0.f,0.f}};
  #pragma unroll
  for (int dir=0; dir<2; ++dir){
    #pragma unroll
    for (int it=0; it<8; ++it){
      int e = it*256 + tid;
      int c = e >> 5, qq = e & 31;
      float4 w = *(const float4*)(ow + ((size_t)(dir*DM + c))*DI + qq*4);
      bf16x4v hv; hv[0]=(__bf16)w.x; hv[1]=(__bf16)w.y; hv[2]=(__bf16)w.z; hv[3]=(__bf16)w.w;
      *(bf16x4v*)(sW + ((c*256 + qq*8) ^ ((c&7)<<4))) = hv;
    }
    __syncthreads();
    #pragma unroll
    for (int t=0; t<2; ++t){
      int T = wv*2 + t, mt = T >> 2, nt = T & 3;
      #pragma unroll
      for (int ktl=0; ktl<4; ++ktl){
        int row = mt*16 + (lane&15);
        bf16x8v av = *(const bf16x8v*)(sY + ((row*512 + dir*256 + ktl*64 + (lane>>4)*16) ^ ((row&7)<<4)));
        int ch = nt*16 + (lane&15);
        bf16x8v wvv = *(const bf16x8v*)(sW + ((ch*256 + ktl*64 + (lane>>4)*16) ^ ((ch&7)<<4)));
        acc2[t] = __builtin_amdgcn_mfma_f32_16x16x32_bf16(av, wvv, acc2[t], 0,0,0);
      }
    }
    __syncthreads();
  }
  #pragma unroll
  for (int t=0; t<2; ++t){
    int T = wv*2 + t, mt = T >> 2, nt = T & 3;
    #pragma unroll
    for (int r=0; r<4; ++r){
      int m = mt*16 + (lane>>4)*4 + r;
      int ch = nt*16 + (lane&15);
      out[((size_t)b*Lx + (size_t)(l0+m))*DM + ch] = acc2[t][r];
    }
  }
}

extern "C" void kernel_launch(void* const* d_in, const int* in_sizes, int n_in,
                              void* d_out, int out_size, void* d_ws, size_t ws_size,
                              hipStream_t stream)
{
  const float* x      = (const float*)d_in[0];
  const float* ln_g   = (const float*)d_in[1];
  const float* ln_b   = (const float*)d_in[2];
  const float* in_w   = (const float*)d_in[3];
  const float* conv_w = (const float*)d_in[4];
  const float* conv_b = (const float*)d_in[5];
  const float* xp_w   = (const float*)d_in[6];
  const float* dtp_w  = (const float*)d_in[7];
  const float* dt_b   = (const float*)d_in[8];
  const float* A_log  = (const float*)d_in[9];
  const float* Dp     = (const float*)d_in[10];
  const float* ow     = (const float*)d_in[11];
  float* out = (float*)d_out;
  float* ws = (float*)d_ws;
  const size_t NBD = (size_t)Bsz*2*Lx*DI;     // 8,388,608
  const size_t NBN = (size_t)Bsz*2*Lx*NS;     // 1,048,576
  float* xcg = ws;                 // xc -> S (in place, ks_scan)
  float* dtg = xcg + NBD;          // dt -> y_local (in place, ks_scan)
  float* zg  = dtg + NBD;
  float* Bg  = zg + NBD;
  float* Cg  = Bg + NBN;
  float* Pm  = Cg + NBN;           // chunk P; becomes h0 in-place after kc
  float* he  = out;                // hend staged in d_out (overwritten by ke)

  a1_front<<<dim3(Bsz*2*(Lx/64)), dim3(512), 0, stream>>>(
      x, ln_g, ln_b, in_w, conv_w, conv_b, xp_w, dtp_w, dt_b, xcg, dtg, zg, Bg, Cg);
  ks_scan<<<dim3(Bsz*2*NC), dim3(256), 0, stream>>>(dtg, xcg, Bg, Cg, A_log, Dp, Pm, he);
  kc_pass2<<<dim3(Bsz*2), dim3(256), 0, stream>>>(Pm, he);
  ke_out<<<dim3(Bsz*(Lx/32)), dim3(256), 0, stream>>>(
      dtg, xcg, zg, Cg, Pm, A_log, ow, out);
}

// Round 25
// 121.598 us; speedup vs baseline: 1.0261x; 1.0250x over previous
//
#include <hip/hip_runtime.h>

#define Bsz 8
#define Lx 4096
#define DM 64
#define DI 128
#define NS 16
#define RK 4
#define KC 4
#define NC 64
#define CT 64

typedef __attribute__((ext_vector_type(8))) __bf16 bf16x8v;
typedef __attribute__((ext_vector_type(4))) __bf16 bf16x4v;
typedef __attribute__((ext_vector_type(4))) float f32x4;

__device__ __forceinline__ float fsig(float x){ return 1.f/(1.f+__expf(-x)); }
__device__ __forceinline__ float dot4(float4 a, float4 b){
  return fmaf(a.x,b.x, fmaf(a.y,b.y, fmaf(a.z,b.z, a.w*b.w)));
}
// powers e1^(n0+1)..e1^(n0+8), log-depth
__device__ __forceinline__ void pow8(float e1, int half, float p[8]){
  float e2=e1*e1, e4=e2*e2, e8=e4*e4;
  if (half){
    p[0]=e8*e1; p[1]=e8*e2; p[2]=p[1]*e1; p[3]=e8*e4;
    p[4]=p[3]*e1; p[5]=p[3]*e2; p[6]=p[5]*e1; p[7]=e8*e8;
  } else {
    p[0]=e1; p[1]=e2; p[2]=e2*e1; p[3]=e4;
    p[4]=e4*e1; p[5]=e4*e2; p[6]=p[5]*e1; p[7]=e8;
  }
}

// ---------------------------------------------------------------------------
// A1 v14: round-22 structure; z stored BF16 (gate-only value; halves z traffic)
// ---------------------------------------------------------------------------
__global__ __launch_bounds__(512) void a1_front(
    const float* __restrict__ x, const float* __restrict__ ln_g, const float* __restrict__ ln_b,
    const float* __restrict__ in_w, const float* __restrict__ conv_w, const float* __restrict__ conv_b,
    const float* __restrict__ xp_w, const float* __restrict__ dtp_w, const float* __restrict__ dt_b,
    float* __restrict__ xcg, float* __restrict__ dtg, __bf16* __restrict__ zgh,
    float* __restrict__ Bg, float* __restrict__ Cg)
{
  __shared__ float uA[4864];
  __shared__ float uB[4096];
  const int tid = threadIdx.x;
  const int bx = blockIdx.x;
  const int tile = bx & 63;
  const int i = (bx >> 6) & 1;
  const int b = bx >> 7;
  const int l0 = tile * 64;
  const size_t rbase = (size_t)(b*2+i)*Lx + l0;
  const int lane = tid & 63, wv = tid >> 6;

  {
    const float gg = ln_g[lane], bb = ln_b[lane];
    for (int lr = wv; lr < 67; lr += 8) {
      float v = 0.f;
      int l = l0 - 3 + lr;
      if (l >= 0) {
        int pl = i ? (Lx-1-l) : l;
        v = x[((size_t)b*Lx + pl)*DM + lane];
        float s = v, s2 = v*v;
        #pragma unroll
        for (int off=32; off; off>>=1){ s += __shfl_xor(s,off); s2 += __shfl_xor(s2,off); }
        float mu = s * (1.f/DM);
        float rs = rsqrtf(s2*(1.f/DM) - mu*mu + 1e-5f);
        v = (v-mu)*rs*gg + bb;
      }
      *(__bf16*)((char*)uA + ((lr*128 + lane*2) ^ ((lr&7)<<4))) = (__bf16)v;
    }
  }
  __syncthreads();

  f32x4 acc[5][2];
  {
    f32x4 z4v = {0.f, 0.f, 0.f, 0.f};
    #pragma unroll
    for (int mt=0; mt<5; ++mt){ acc[mt][0] = z4v; acc[mt][1] = z4v; }
    #pragma unroll
    for (int p = 0; p < 2; ++p) {
      #pragma unroll
      for (int it=0; it<4; ++it) {
        int g = it*512 + tid;
        int c = g >> 4, q = g & 15;
        float4 w = *(const float4*)(in_w + ((size_t)(i*2*DI) + p*DI + c)*DM + q*4);
        bf16x4v hv;
        hv[0]=(__bf16)w.x; hv[1]=(__bf16)w.y; hv[2]=(__bf16)w.z; hv[3]=(__bf16)w.w;
        *(bf16x4v*)((char*)uB + ((c*128 + q*8) ^ ((c&7)<<4))) = hv;
      }
      __syncthreads();
      bf16x8v bfr[2];
      #pragma unroll
      for (int kt=0; kt<2; ++kt){
        int cl = wv*16 + (lane&15);
        int byt = (cl*128 + kt*64 + (lane>>4)*16) ^ ((cl&7)<<4);
        bfr[kt] = *(const bf16x8v*)((const char*)uB + byt);
      }
      #pragma unroll
      for (int mt=0; mt<5; ++mt){
        bf16x8v afr[2];
        #pragma unroll
        for (int kt=0; kt<2; ++kt){
          int row = mt*16 + (lane&15);
          int byt = (row*128 + kt*64 + (lane>>4)*16) ^ ((row&7)<<4);
          afr[kt] = *(const bf16x8v*)((const char*)uA + byt);
        }
        acc[mt][p] = __builtin_amdgcn_mfma_f32_16x16x32_bf16(afr[0], bfr[0], acc[mt][p], 0,0,0);
        acc[mt][p] = __builtin_amdgcn_mfma_f32_16x16x32_bf16(afr[1], bfr[1], acc[mt][p], 0,0,0);
      }
      __syncthreads();
    }
  }

  {
    const int d0 = wv*16 + (lane&15);
    const int d = tid & 127, rh = tid >> 7;
    const float4 cw = *(const float4*)(conv_w + (size_t)(i*DI + d)*KC);
    const float cb = conv_b[i*DI + d];
    #pragma unroll
    for (int h=0; h<2; ++h) {
      #pragma unroll
      for (int mt=0; mt<5; ++mt)
        #pragma unroll
        for (int r=0; r<4; ++r){
          int m = mt*16 + (lane>>4)*4 + r;
          if (m >= h*32 && m <= h*32+34)
            uA[(m - h*32)*129 + d0] = acc[mt][0][r];
        }
      if (h == 0) {
        #pragma unroll
        for (int mt=0; mt<5; ++mt)
          #pragma unroll
          for (int r=0; r<4; ++r){
            int m = mt*16 + (lane>>4)*4 + r;
            if (m >= 3 && m <= 66)
              zgh[(rbase + (m-3))*DI + d0] = (__bf16)acc[mt][1][r];
          }
      }
      __syncthreads();
      #pragma unroll
      for (int rr=0; rr<8; ++rr){
        int lb = rh*8 + rr;
        int r = h*32 + lb;
        float v0 = uA[(lb  )*129 + d];
        float v1 = uA[(lb+1)*129 + d];
        float v2 = uA[(lb+2)*129 + d];
        float v3 = uA[(lb+3)*129 + d];
        float aa = cb + cw.x*v0 + cw.y*v1 + cw.z*v2 + cw.w*v3;
        float xc = aa * fsig(aa);
        xcg[(rbase + r)*DI + d] = xc;
        int off = (r*256 + d*2) ^ ((r&7)<<4);
        *(__bf16*)((char*)uB + off) = (__bf16)xc;
      }
      __syncthreads();
    }
  }

  for (int e = tid; e < 36*32; e += 512) {
    int j = e >> 5, k0 = (e & 31)*4;
    float4 w = *(const float4*)(xp_w + ((size_t)(i*36) + j)*DI + k0);
    float vv[4] = {w.x, w.y, w.z, w.w};
    bf16x4v hv, lv;
    #pragma unroll
    for (int k=0;k<4;++k){
      __bf16 hh = (__bf16)vv[k];
      hv[k] = hh;
      lv[k] = (__bf16)(vv[k] - (float)hh);
    }
    int off = (j*256 + k0*2) ^ ((j&7)<<4);
    *(bf16x4v*)((char*)uA + off) = hv;
    *(bf16x4v*)((char*)uA + off + 9216) = lv;
  }
  __syncthreads();

  for (int t = wv; t < 12; t += 8) {
    int mt = t & 3, nt = t >> 2;
    f32x4 a2 = {0.f,0.f,0.f,0.f};
    #pragma unroll
    for (int kt=0; kt<4; ++kt){
      int row = mt*16 + (lane&15);
      int ab = (row*256 + kt*64 + (lane>>4)*16) ^ ((row&7)<<4);
      bf16x8v ah = *(const bf16x8v*)((const char*)uB + ab);
      int col = nt*16 + (lane&15);
      int bby = (col*256 + kt*64 + (lane>>4)*16) ^ ((col&7)<<4);
      bf16x8v bh = *(const bf16x8v*)((const char*)uA + bby);
      bf16x8v bl = *(const bf16x8v*)((const char*)uA + bby + 9216);
      a2 = __builtin_amdgcn_mfma_f32_16x16x32_bf16(ah, bh, a2, 0,0,0);
      a2 = __builtin_amdgcn_mfma_f32_16x16x32_bf16(ah, bl, a2, 0,0,0);
    }
    #pragma unroll
    for (int rg4=0; rg4<4; ++rg4){
      int row = mt*16 + (lane>>4)*4 + rg4;
      int j = nt*16 + (lane&15);
      float val = a2[rg4];
      if (j < 4) uA[4608 + row*4 + j] = val;
      else if (j < 20) Bg[(rbase+row)*NS + (j-4)] = val;
      else if (j < 36) Cg[(rbase+row)*NS + (j-20)] = val;
    }
  }
  __syncthreads();

  #pragma unroll 4
  for (int it=0; it<16; ++it) {
    int e = it*512 + tid;
    int r = e >> 7, d = e & 127;
    float4 dl = *(const float4*)&uA[4608 + r*4];
    float4 w  = *(const float4*)(dtp_w + (size_t)(i*DI + d)*RK);
    float a = dt_b[i*DI + d] + dot4(w, dl);
    dtg[(rbase + r)*DI + d] = (a > 15.f) ? a : __logf(1.f + __expf(a));
  }
}

// ---------------------------------------------------------------------------
// KS v2 (proven): local scan, B/C in LDS + dt/x double-buffer.
// ---------------------------------------------------------------------------
__global__ __launch_bounds__(256) void ks_scan(
    float* dtg, float* xcg,
    const float* __restrict__ Bg, const float* __restrict__ Cg,
    const float* __restrict__ A_log, const float* __restrict__ Dp,
    float* __restrict__ Pm, float* __restrict__ hend)
{
  __shared__ float sB[CT*NS];
  __shared__ float sC[CT*NS];
  const int tid = threadIdx.x;
  const int bx = blockIdx.x;
  const int c = bx % NC; const int i = (bx/NC)&1; const int b = bx/(2*NC);
  const int d = tid >> 1, half = tid & 1, n0 = half*8;
  const size_t rb = ((size_t)(b*2+i)*Lx + (size_t)c*CT);
  ((float4*)sB)[tid] = ((const float4*)(Bg + rb*NS))[tid];
  ((float4*)sC)[tid] = ((const float4*)(Cg + rb*NS))[tid];
  float a[8], h[8];
  bool afast = true;
  #pragma unroll
  for (int n=0;n<8;++n){
    a[n] = -__expf(A_log[((size_t)(i*DI)+d)*NS + n0+n]);
    float tgt = (float)(n0+n+1);
    afast = afast && (fabsf(a[n] + tgt) <= 1e-4f*tgt);
    h[n] = 0.f;
  }
  const float Dd = Dp[i*DI + d];
  float S = 0.f;
  float dt4[4], x4[4];
  #pragma unroll
  for (int k=0;k<4;++k){
    size_t g = (rb + k)*DI + d;
    dt4[k] = dtg[g];
    x4[k]  = xcg[g];
  }
  __syncthreads();
  for (int r4 = 0; r4 < CT; r4 += 4){
    float dtn[4], xn[4];
    if (r4 + 4 < CT){
      #pragma unroll
      for (int k=0;k<4;++k){
        size_t g = (rb + r4 + 4 + k)*DI + d;
        dtn[k] = dtg[g];
        xn[k]  = xcg[g];
      }
    }
    #pragma unroll
    for (int k=0;k<4;++k){
      float dtt = dt4[k];
      float xcv = x4[k];
      float u = dtt * xcv;
      S += dtt;
      const float* bp = &sB[(r4 + k)*NS + n0];
      const float* cp = &sC[(r4 + k)*NS + n0];
      float4 b0 = *(const float4*)bp;
      float4 b1 = *(const float4*)(bp+4);
      float4 c0 = *(const float4*)cp;
      float4 c1 = *(const float4*)(cp+4);
      float bb[8] = {b0.x,b0.y,b0.z,b0.w,b1.x,b1.y,b1.z,b1.w};
      float cc[8] = {c0.x,c0.y,c0.z,c0.w,c1.x,c1.y,c1.z,c1.w};
      float pA = 0.f, pB = 0.f;
      if (afast){
        float p[8];
        pow8(__expf(-dtt), half, p);
        #pragma unroll
        for (int n=0;n<8;++n){
          h[n] = fmaf(p[n], h[n], u*bb[n]);
          if (n & 1) pB = fmaf(h[n], cc[n], pB); else pA = fmaf(h[n], cc[n], pA);
        }
      } else {
        #pragma unroll
        for (int n=0;n<8;++n){
          float dA = __expf(a[n]*dtt);
          h[n] = fmaf(dA, h[n], u*bb[n]);
          if (n & 1) pB = fmaf(h[n], cc[n], pB); else pA = fmaf(h[n], cc[n], pA);
        }
      }
      float part = pA + pB;
      float y = part + __shfl_xor(part, 1);
      if (half == 0){
        size_t g = (rb + r4 + k)*DI + d;
        dtg[g] = fmaf(xcv, Dd, y);
        xcg[g] = S;
      }
    }
    if (r4 + 4 < CT){
      #pragma unroll
      for (int k=0;k<4;++k){ dt4[k] = dtn[k]; x4[k] = xn[k]; }
    }
  }
  size_t ob = (((size_t)(b*2+i)*NC + c)*DI + d)*NS + n0;
  if (afast){
    float p[8];
    pow8(__expf(-S), half, p);
    #pragma unroll
    for (int n=0;n<8;++n) Pm[ob+n] = p[n];
  } else {
    #pragma unroll
    for (int n=0;n<8;++n) Pm[ob+n] = __expf(a[n]*S);
  }
  #pragma unroll
  for (int n=0;n<8;++n) hend[ob+n] = h[n];
}

// ---------------------------------------------------------------------------
// KC v2: chunk propagation with prefetch (in-place h0 over Pm)
// ---------------------------------------------------------------------------
__global__ __launch_bounds__(256) void kc_pass2(
    float* __restrict__ Pm, const float* __restrict__ hend)
{
  const int tid = threadIdx.x;
  const int bi = blockIdx.x;
  const int d = tid>>1, n0 = (tid&1)*8;
  float h[8];
  #pragma unroll
  for (int n=0;n<8;++n) h[n]=0.f;
  const size_t stride = (size_t)DI*NS;
  size_t ob = (((size_t)bi*NC)*DI + d)*NS + n0;
  float4 pa = *(const float4*)&Pm[ob],   pb = *(const float4*)&Pm[ob+4];
  float4 ea = *(const float4*)&hend[ob], eb = *(const float4*)&hend[ob+4];
  for (int c=0; c<NC; ++c){
    size_t obn = ob + stride;
    float4 qa=pa, qb=pb, fa=ea, fb=eb;
    if (c+1 < NC){
      qa = *(const float4*)&Pm[obn];   qb = *(const float4*)&Pm[obn+4];
      fa = *(const float4*)&hend[obn]; fb = *(const float4*)&hend[obn+4];
    }
    *(float4*)&Pm[ob]   = make_float4(h[0],h[1],h[2],h[3]);
    *(float4*)&Pm[ob+4] = make_float4(h[4],h[5],h[6],h[7]);
    h[0]=fmaf(pa.x,h[0],ea.x); h[1]=fmaf(pa.y,h[1],ea.y);
    h[2]=fmaf(pa.z,h[2],ea.z); h[3]=fmaf(pa.w,h[3],ea.w);
    h[4]=fmaf(pb.x,h[4],eb.x); h[5]=fmaf(pb.y,h[5],eb.y);
    h[6]=fmaf(pb.z,h[6],eb.z); h[7]=fmaf(pb.w,h[7],eb.w);
    pa=qa; pb=qb; ea=fa; eb=fb; ob = obn;
  }
}

// ---------------------------------------------------------------------------
// KE v9: round-22 ke v8 + bf16 z reads (8B per thread, coalesced).
// ---------------------------------------------------------------------------
__global__ __launch_bounds__(256) void ke_out(
    const float* __restrict__ yg, const float* __restrict__ Sg,
    const __bf16* __restrict__ zgh, const float* __restrict__ Cg,
    const float* __restrict__ h0g, const float* __restrict__ A_log,
    const float* __restrict__ ow, float* __restrict__ out)
{
  __shared__ char sY[16384];
  __shared__ char sW[16384];
  __shared__ float sH[2*128*17];
  __shared__ int s_af[2];
  const int tid = threadIdx.x;
  const int bx = blockIdx.x;
  const int tile = bx & 127; const int b = bx >> 7;
  const int l0 = tile * 32;
  const int q = tid & 31, rg = tid >> 5;
  if (tid < 2) s_af[tid] = 1;
  bool bad0 = false, bad1 = false;
  #pragma unroll
  for (int it=0; it<8; ++it){
    int e = it*256 + tid;
    int n = e & 15;
    float tgt = (float)(n+1);
    float a0 = __expf(A_log[e]);
    float a1 = __expf(A_log[DI*NS + e]);
    if (fabsf(a0 - tgt) > 1e-4f*tgt) bad0 = true;
    if (fabsf(a1 - tgt) > 1e-4f*tgt) bad1 = true;
  }
  {
    const int cch0 = (l0 >> 6), cch1 = ((Lx-1-l0) >> 6);
    #pragma unroll
    for (int it=0; it<4; ++it){
      int f = it*256 + tid;
      int dir = f >> 9, rem = f & 511;
      int dd = rem >> 2, k = rem & 3;
      size_t strm = (size_t)(b*2+dir);
      int cch = dir ? cch1 : cch0;
      float4 v = *(const float4*)&h0g[(((strm*NC)+cch)*DI + dd)*NS + k*4];
      float* hp = &sH[dir*2176 + dd*17 + k*4];
      hp[0]=v.x; hp[1]=v.y; hp[2]=v.z; hp[3]=v.w;
    }
  }
  __syncthreads();
  if (bad0) s_af[0] = 0;
  if (bad1) s_af[1] = 0;
  __syncthreads();
  const bool af0 = (s_af[0] != 0), af1 = (s_af[1] != 0);
  #pragma unroll
  for (int dir=0; dir<2; ++dir){
    const size_t strm = (size_t)(b*2+dir);
    const bool afast = dir ? af1 : af0;
    float h0q[4][16];
    #pragma unroll
    for (int dd=0; dd<4; ++dd){
      const float* hp = &sH[dir*2176 + (q*4+dd)*17];
      #pragma unroll
      for (int n=0;n<16;++n) h0q[dd][n] = hp[n];
    }
    #pragma unroll
    for (int it=0; it<4; ++it){
      int r = it*8 + rg;
      size_t prow = strm*Lx + (size_t)(dir ? (Lx-1-(l0+r)) : (l0+r));
      float4 y4 = *(const float4*)&yg[prow*DI + q*4];
      float4 S4 = *(const float4*)&Sg[prow*DI + q*4];
      bf16x4v zb = *(const bf16x4v*)&zgh[prow*DI + q*4];
      float c16[16];
      #pragma unroll
      for (int k=0;k<4;++k) *(float4*)&c16[k*4] = *(const float4*)&Cg[prow*NS + k*4];
      float yv[4] = {y4.x,y4.y,y4.z,y4.w};
      float Sv[4] = {S4.x,S4.y,S4.z,S4.w};
      float zv[4] = {(float)zb[0],(float)zb[1],(float)zb[2],(float)zb[3]};
      bf16x4v hv;
      #pragma unroll
      for (int dd=0; dd<4; ++dd){
        float corr;
        if (afast){
          float e1 = __expf(-Sv[dd]);
          float g[16];
          #pragma unroll
          for (int n=0;n<16;++n) g[n] = c16[n]*h0q[dd][n];
          float t = g[15];
          #pragma unroll
          for (int n=14;n>=0;--n) t = fmaf(t, e1, g[n]);
          corr = t * e1;
        } else {
          corr = 0.f;
          #pragma unroll
          for (int n=0;n<16;++n){
            float an = -__expf(A_log[((size_t)(dir*DI) + q*4+dd)*NS + n]);
            corr = fmaf(__expf(an*Sv[dd])*c16[n], h0q[dd][n], corr);
          }
        }
        float zz = zv[dd];
        float yf = (yv[dd] + corr) * (zz * fsig(zz));
        hv[dd] = (__bf16)yf;
      }
      *(bf16x4v*)(sY + ((r*512 + dir*256 + q*8) ^ ((r&7)<<4))) = hv;
    }
  }
  __syncthreads();
  const int lane = tid & 63, wv = tid >> 6;
  f32x4 acc2[2] = {{0.f,0.f,0.f,0.f},{0.f,0.f,0.f,0.f}};
  #pragma unroll
  for (int dir=0; dir<2; ++dir){
    #pragma unroll
    for (int it=0; it<8; ++it){
      int e = it*256 + tid;
      int c = e >> 5, qq = e & 31;
      float4 w = *(const float4*)(ow + ((size_t)(dir*DM + c))*DI + qq*4);
      bf16x4v hv; hv[0]=(__bf16)w.x; hv[1]=(__bf16)w.y; hv[2]=(__bf16)w.z; hv[3]=(__bf16)w.w;
      *(bf16x4v*)(sW + ((c*256 + qq*8) ^ ((c&7)<<4))) = hv;
    }
    __syncthreads();
    #pragma unroll
    for (int t=0; t<2; ++t){
      int T = wv*2 + t, mt = T >> 2, nt = T & 3;
      #pragma unroll
      for (int ktl=0; ktl<4; ++ktl){
        int row = mt*16 + (lane&15);
        bf16x8v av = *(const bf16x8v*)(sY + ((row*512 + dir*256 + ktl*64 + (lane>>4)*16) ^ ((row&7)<<4)));
        int ch = nt*16 + (lane&15);
        bf16x8v wvv = *(const bf16x8v*)(sW + ((ch*256 + ktl*64 + (lane>>4)*16) ^ ((ch&7)<<4)));
        acc2[t] = __builtin_amdgcn_mfma_f32_16x16x32_bf16(av, wvv, acc2[t], 0,0,0);
      }
    }
    __syncthreads();
  }
  #pragma unroll
  for (int t=0; t<2; ++t){
    int T = wv*2 + t, mt = T >> 2, nt = T & 3;
    #pragma unroll
    for (int r=0; r<4; ++r){
      int m = mt*16 + (lane>>4)*4 + r;
      int ch = nt*16 + (lane&15);
      out[((size_t)b*Lx + (size_t)(l0+m))*DM + ch] = acc2[t][r];
    }
  }
}

extern "C" void kernel_launch(void* const* d_in, const int* in_sizes, int n_in,
                              void* d_out, int out_size, void* d_ws, size_t ws_size,
                              hipStream_t stream)
{
  const float* x      = (const float*)d_in[0];
  const float* ln_g   = (const float*)d_in[1];
  const float* ln_b   = (const float*)d_in[2];
  const float* in_w   = (const float*)d_in[3];
  const float* conv_w = (const float*)d_in[4];
  const float* conv_b = (const float*)d_in[5];
  const float* xp_w   = (const float*)d_in[6];
  const float* dtp_w  = (const float*)d_in[7];
  const float* dt_b   = (const float*)d_in[8];
  const float* A_log  = (const float*)d_in[9];
  const float* Dp     = (const float*)d_in[10];
  const float* ow     = (const float*)d_in[11];
  float* out = (float*)d_out;
  float* ws = (float*)d_ws;
  const size_t NBD = (size_t)Bsz*2*Lx*DI;     // 8,388,608
  const size_t NBN = (size_t)Bsz*2*Lx*NS;     // 1,048,576
  float* xcg = ws;                 // xc -> S (in place, ks_scan)
  float* dtg = xcg + NBD;          // dt -> y_local (in place, ks_scan)
  __bf16* zgh = (__bf16*)(dtg + NBD);          // z, bf16 (NBD/2 floats)
  float* Bg  = dtg + NBD + NBD/2;
  float* Cg  = Bg + NBN;
  float* Pm  = Cg + NBN;           // chunk P; becomes h0 in-place after kc
  float* he  = out;                // hend staged in d_out (overwritten by ke)

  a1_front<<<dim3(Bsz*2*(Lx/64)), dim3(512), 0, stream>>>(
      x, ln_g, ln_b, in_w, conv_w, conv_b, xp_w, dtp_w, dt_b, xcg, dtg, zgh, Bg, Cg);
  ks_scan<<<dim3(Bsz*2*NC), dim3(256), 0, stream>>>(dtg, xcg, Bg, Cg, A_log, Dp, Pm, he);
  kc_pass2<<<dim3(Bsz*2), dim3(256), 0, stream>>>(Pm, he);
  ke_out<<<dim3(Bsz*(Lx/32)), dim3(256), 0, stream>>>(
      dtg, xcg, zgh, Cg, Pm, A_log, ow, out);
}

// Round 26
// 119.491 us; speedup vs baseline: 1.0442x; 1.0176x over previous
//
#include <hip/hip_runtime.h>

#define Bsz 8
#define Lx 4096
#define DM 64
#define DI 128
#define NS 16
#define RK 4
#define KC 4
#define NC 64
#define CT 64

typedef __attribute__((ext_vector_type(8))) __bf16 bf16x8v;
typedef __attribute__((ext_vector_type(4))) __bf16 bf16x4v;
typedef __attribute__((ext_vector_type(4))) float f32x4;

__device__ __forceinline__ float fsig(float x){ return 1.f/(1.f+__expf(-x)); }
__device__ __forceinline__ float dot4(float4 a, float4 b){
  return fmaf(a.x,b.x, fmaf(a.y,b.y, fmaf(a.z,b.z, a.w*b.w)));
}
// powers e1^(n0+1)..e1^(n0+8), log-depth
__device__ __forceinline__ void pow8(float e1, int half, float p[8]){
  float e2=e1*e1, e4=e2*e2, e8=e4*e4;
  if (half){
    p[0]=e8*e1; p[1]=e8*e2; p[2]=p[1]*e1; p[3]=e8*e4;
    p[4]=p[3]*e1; p[5]=p[3]*e2; p[6]=p[5]*e1; p[7]=e8*e8;
  } else {
    p[0]=e1; p[1]=e2; p[2]=e2*e1; p[3]=e4;
    p[4]=e4*e1; p[5]=e4*e2; p[6]=p[5]*e1; p[7]=e8;
  }
}

// ---------------------------------------------------------------------------
// A1 v14 (round-25 proven): 2-half W staging, xc-hi x_proj, bf16 z.
// ---------------------------------------------------------------------------
__global__ __launch_bounds__(512) void a1_front(
    const float* __restrict__ x, const float* __restrict__ ln_g, const float* __restrict__ ln_b,
    const float* __restrict__ in_w, const float* __restrict__ conv_w, const float* __restrict__ conv_b,
    const float* __restrict__ xp_w, const float* __restrict__ dtp_w, const float* __restrict__ dt_b,
    float* __restrict__ xcg, float* __restrict__ dtg, __bf16* __restrict__ zgh,
    float* __restrict__ Bg, float* __restrict__ Cg)
{
  __shared__ float uA[4864];
  __shared__ float uB[4096];
  const int tid = threadIdx.x;
  const int bx = blockIdx.x;
  const int tile = bx & 63;
  const int i = (bx >> 6) & 1;
  const int b = bx >> 7;
  const int l0 = tile * 64;
  const size_t rbase = (size_t)(b*2+i)*Lx + l0;
  const int lane = tid & 63, wv = tid >> 6;

  {
    const float gg = ln_g[lane], bb = ln_b[lane];
    for (int lr = wv; lr < 67; lr += 8) {
      float v = 0.f;
      int l = l0 - 3 + lr;
      if (l >= 0) {
        int pl = i ? (Lx-1-l) : l;
        v = x[((size_t)b*Lx + pl)*DM + lane];
        float s = v, s2 = v*v;
        #pragma unroll
        for (int off=32; off; off>>=1){ s += __shfl_xor(s,off); s2 += __shfl_xor(s2,off); }
        float mu = s * (1.f/DM);
        float rs = rsqrtf(s2*(1.f/DM) - mu*mu + 1e-5f);
        v = (v-mu)*rs*gg + bb;
      }
      *(__bf16*)((char*)uA + ((lr*128 + lane*2) ^ ((lr&7)<<4))) = (__bf16)v;
    }
  }
  __syncthreads();

  f32x4 acc[5][2];
  {
    f32x4 z4v = {0.f, 0.f, 0.f, 0.f};
    #pragma unroll
    for (int mt=0; mt<5; ++mt){ acc[mt][0] = z4v; acc[mt][1] = z4v; }
    #pragma unroll
    for (int p = 0; p < 2; ++p) {
      #pragma unroll
      for (int it=0; it<4; ++it) {
        int g = it*512 + tid;
        int c = g >> 4, q = g & 15;
        float4 w = *(const float4*)(in_w + ((size_t)(i*2*DI) + p*DI + c)*DM + q*4);
        bf16x4v hv;
        hv[0]=(__bf16)w.x; hv[1]=(__bf16)w.y; hv[2]=(__bf16)w.z; hv[3]=(__bf16)w.w;
        *(bf16x4v*)((char*)uB + ((c*128 + q*8) ^ ((c&7)<<4))) = hv;
      }
      __syncthreads();
      bf16x8v bfr[2];
      #pragma unroll
      for (int kt=0; kt<2; ++kt){
        int cl = wv*16 + (lane&15);
        int byt = (cl*128 + kt*64 + (lane>>4)*16) ^ ((cl&7)<<4);
        bfr[kt] = *(const bf16x8v*)((const char*)uB + byt);
      }
      #pragma unroll
      for (int mt=0; mt<5; ++mt){
        bf16x8v afr[2];
        #pragma unroll
        for (int kt=0; kt<2; ++kt){
          int row = mt*16 + (lane&15);
          int byt = (row*128 + kt*64 + (lane>>4)*16) ^ ((row&7)<<4);
          afr[kt] = *(const bf16x8v*)((const char*)uA + byt);
        }
        acc[mt][p] = __builtin_amdgcn_mfma_f32_16x16x32_bf16(afr[0], bfr[0], acc[mt][p], 0,0,0);
        acc[mt][p] = __builtin_amdgcn_mfma_f32_16x16x32_bf16(afr[1], bfr[1], acc[mt][p], 0,0,0);
      }
      __syncthreads();
    }
  }

  {
    const int d0 = wv*16 + (lane&15);
    const int d = tid & 127, rh = tid >> 7;
    const float4 cw = *(const float4*)(conv_w + (size_t)(i*DI + d)*KC);
    const float cb = conv_b[i*DI + d];
    #pragma unroll
    for (int h=0; h<2; ++h) {
      #pragma unroll
      for (int mt=0; mt<5; ++mt)
        #pragma unroll
        for (int r=0; r<4; ++r){
          int m = mt*16 + (lane>>4)*4 + r;
          if (m >= h*32 && m <= h*32+34)
            uA[(m - h*32)*129 + d0] = acc[mt][0][r];
        }
      if (h == 0) {
        #pragma unroll
        for (int mt=0; mt<5; ++mt)
          #pragma unroll
          for (int r=0; r<4; ++r){
            int m = mt*16 + (lane>>4)*4 + r;
            if (m >= 3 && m <= 66)
              zgh[(rbase + (m-3))*DI + d0] = (__bf16)acc[mt][1][r];
          }
      }
      __syncthreads();
      #pragma unroll
      for (int rr=0; rr<8; ++rr){
        int lb = rh*8 + rr;
        int r = h*32 + lb;
        float v0 = uA[(lb  )*129 + d];
        float v1 = uA[(lb+1)*129 + d];
        float v2 = uA[(lb+2)*129 + d];
        float v3 = uA[(lb+3)*129 + d];
        float aa = cb + cw.x*v0 + cw.y*v1 + cw.z*v2 + cw.w*v3;
        float xc = aa * fsig(aa);
        xcg[(rbase + r)*DI + d] = xc;
        int off = (r*256 + d*2) ^ ((r&7)<<4);
        *(__bf16*)((char*)uB + off) = (__bf16)xc;
      }
      __syncthreads();
    }
  }

  for (int e = tid; e < 36*32; e += 512) {
    int j = e >> 5, k0 = (e & 31)*4;
    float4 w = *(const float4*)(xp_w + ((size_t)(i*36) + j)*DI + k0);
    float vv[4] = {w.x, w.y, w.z, w.w};
    bf16x4v hv, lv;
    #pragma unroll
    for (int k=0;k<4;++k){
      __bf16 hh = (__bf16)vv[k];
      hv[k] = hh;
      lv[k] = (__bf16)(vv[k] - (float)hh);
    }
    int off = (j*256 + k0*2) ^ ((j&7)<<4);
    *(bf16x4v*)((char*)uA + off) = hv;
    *(bf16x4v*)((char*)uA + off + 9216) = lv;
  }
  __syncthreads();

  for (int t = wv; t < 12; t += 8) {
    int mt = t & 3, nt = t >> 2;
    f32x4 a2 = {0.f,0.f,0.f,0.f};
    #pragma unroll
    for (int kt=0; kt<4; ++kt){
      int row = mt*16 + (lane&15);
      int ab = (row*256 + kt*64 + (lane>>4)*16) ^ ((row&7)<<4);
      bf16x8v ah = *(const bf16x8v*)((const char*)uB + ab);
      int col = nt*16 + (lane&15);
      int bby = (col*256 + kt*64 + (lane>>4)*16) ^ ((col&7)<<4);
      bf16x8v bh = *(const bf16x8v*)((const char*)uA + bby);
      bf16x8v bl = *(const bf16x8v*)((const char*)uA + bby + 9216);
      a2 = __builtin_amdgcn_mfma_f32_16x16x32_bf16(ah, bh, a2, 0,0,0);
      a2 = __builtin_amdgcn_mfma_f32_16x16x32_bf16(ah, bl, a2, 0,0,0);
    }
    #pragma unroll
    for (int rg4=0; rg4<4; ++rg4){
      int row = mt*16 + (lane>>4)*4 + rg4;
      int j = nt*16 + (lane&15);
      float val = a2[rg4];
      if (j < 4) uA[4608 + row*4 + j] = val;
      else if (j < 20) Bg[(rbase+row)*NS + (j-4)] = val;
      else if (j < 36) Cg[(rbase+row)*NS + (j-20)] = val;
    }
  }
  __syncthreads();

  #pragma unroll 4
  for (int it=0; it<16; ++it) {
    int e = it*512 + tid;
    int r = e >> 7, d = e & 127;
    float4 dl = *(const float4*)&uA[4608 + r*4];
    float4 w  = *(const float4*)(dtp_w + (size_t)(i*DI + d)*RK);
    float a = dt_b[i*DI + d] + dot4(w, dl);
    dtg[(rbase + r)*DI + d] = (a > 15.f) ? a : __logf(1.f + __expf(a));
  }
}

// ---------------------------------------------------------------------------
// KS v4: local scan; y_local written BF16 to ybh (ke re-rounds to bf16 anyway),
// S fp32 in-place over xcg. dtg now read-only.
// ---------------------------------------------------------------------------
__global__ __launch_bounds__(256) void ks_scan(
    const float* __restrict__ dtg, float* xcg, __bf16* __restrict__ ybh,
    const float* __restrict__ Bg, const float* __restrict__ Cg,
    const float* __restrict__ A_log, const float* __restrict__ Dp,
    float* __restrict__ Pm, float* __restrict__ hend)
{
  __shared__ float sB[CT*NS];
  __shared__ float sC[CT*NS];
  const int tid = threadIdx.x;
  const int bx = blockIdx.x;
  const int c = bx % NC; const int i = (bx/NC)&1; const int b = bx/(2*NC);
  const int d = tid >> 1, half = tid & 1, n0 = half*8;
  const size_t rb = ((size_t)(b*2+i)*Lx + (size_t)c*CT);
  ((float4*)sB)[tid] = ((const float4*)(Bg + rb*NS))[tid];
  ((float4*)sC)[tid] = ((const float4*)(Cg + rb*NS))[tid];
  float a[8], h[8];
  bool afast = true;
  #pragma unroll
  for (int n=0;n<8;++n){
    a[n] = -__expf(A_log[((size_t)(i*DI)+d)*NS + n0+n]);
    float tgt = (float)(n0+n+1);
    afast = afast && (fabsf(a[n] + tgt) <= 1e-4f*tgt);
    h[n] = 0.f;
  }
  const float Dd = Dp[i*DI + d];
  float S = 0.f;
  float dt4[4], x4[4];
  #pragma unroll
  for (int k=0;k<4;++k){
    size_t g = (rb + k)*DI + d;
    dt4[k] = dtg[g];
    x4[k]  = xcg[g];
  }
  __syncthreads();
  for (int r4 = 0; r4 < CT; r4 += 4){
    float dtn[4], xn[4];
    if (r4 + 4 < CT){
      #pragma unroll
      for (int k=0;k<4;++k){
        size_t g = (rb + r4 + 4 + k)*DI + d;
        dtn[k] = dtg[g];
        xn[k]  = xcg[g];
      }
    }
    #pragma unroll
    for (int k=0;k<4;++k){
      float dtt = dt4[k];
      float xcv = x4[k];
      float u = dtt * xcv;
      S += dtt;
      const float* bp = &sB[(r4 + k)*NS + n0];
      const float* cp = &sC[(r4 + k)*NS + n0];
      float4 b0 = *(const float4*)bp;
      float4 b1 = *(const float4*)(bp+4);
      float4 c0 = *(const float4*)cp;
      float4 c1 = *(const float4*)(cp+4);
      float bb[8] = {b0.x,b0.y,b0.z,b0.w,b1.x,b1.y,b1.z,b1.w};
      float cc[8] = {c0.x,c0.y,c0.z,c0.w,c1.x,c1.y,c1.z,c1.w};
      float pA = 0.f, pB = 0.f;
      if (afast){
        float p[8];
        pow8(__expf(-dtt), half, p);
        #pragma unroll
        for (int n=0;n<8;++n){
          h[n] = fmaf(p[n], h[n], u*bb[n]);
          if (n & 1) pB = fmaf(h[n], cc[n], pB); else pA = fmaf(h[n], cc[n], pA);
        }
      } else {
        #pragma unroll
        for (int n=0;n<8;++n){
          float dA = __expf(a[n]*dtt);
          h[n] = fmaf(dA, h[n], u*bb[n]);
          if (n & 1) pB = fmaf(h[n], cc[n], pB); else pA = fmaf(h[n], cc[n], pA);
        }
      }
      float part = pA + pB;
      float y = part + __shfl_xor(part, 1);
      if (half == 0){
        size_t g = (rb + r4 + k)*DI + d;
        ybh[g] = (__bf16)fmaf(xcv, Dd, y);
        xcg[g] = S;
      }
    }
    if (r4 + 4 < CT){
      #pragma unroll
      for (int k=0;k<4;++k){ dt4[k] = dtn[k]; x4[k] = xn[k]; }
    }
  }
  size_t ob = (((size_t)(b*2+i)*NC + c)*DI + d)*NS + n0;
  if (afast){
    float p[8];
    pow8(__expf(-S), half, p);
    #pragma unroll
    for (int n=0;n<8;++n) Pm[ob+n] = p[n];
  } else {
    #pragma unroll
    for (int n=0;n<8;++n) Pm[ob+n] = __expf(a[n]*S);
  }
  #pragma unroll
  for (int n=0;n<8;++n) hend[ob+n] = h[n];
}

// ---------------------------------------------------------------------------
// KC v2: chunk propagation with prefetch (in-place h0 over Pm)
// ---------------------------------------------------------------------------
__global__ __launch_bounds__(256) void kc_pass2(
    float* __restrict__ Pm, const float* __restrict__ hend)
{
  const int tid = threadIdx.x;
  const int bi = blockIdx.x;
  const int d = tid>>1, n0 = (tid&1)*8;
  float h[8];
  #pragma unroll
  for (int n=0;n<8;++n) h[n]=0.f;
  const size_t stride = (size_t)DI*NS;
  size_t ob = (((size_t)bi*NC)*DI + d)*NS + n0;
  float4 pa = *(const float4*)&Pm[ob],   pb = *(const float4*)&Pm[ob+4];
  float4 ea = *(const float4*)&hend[ob], eb = *(const float4*)&hend[ob+4];
  for (int c=0; c<NC; ++c){
    size_t obn = ob + stride;
    float4 qa=pa, qb=pb, fa=ea, fb=eb;
    if (c+1 < NC){
      qa = *(const float4*)&Pm[obn];   qb = *(const float4*)&Pm[obn+4];
      fa = *(const float4*)&hend[obn]; fb = *(const float4*)&hend[obn+4];
    }
    *(float4*)&Pm[ob]   = make_float4(h[0],h[1],h[2],h[3]);
    *(float4*)&Pm[ob+4] = make_float4(h[4],h[5],h[6],h[7]);
    h[0]=fmaf(pa.x,h[0],ea.x); h[1]=fmaf(pa.y,h[1],ea.y);
    h[2]=fmaf(pa.z,h[2],ea.z); h[3]=fmaf(pa.w,h[3],ea.w);
    h[4]=fmaf(pb.x,h[4],eb.x); h[5]=fmaf(pb.y,h[5],eb.y);
    h[6]=fmaf(pb.z,h[6],eb.z); h[7]=fmaf(pb.w,h[7],eb.w);
    pa=qa; pb=qb; ea=fa; eb=fb; ob = obn;
  }
}

// ---------------------------------------------------------------------------
// KE v10: bf16 y_local + bf16 z reads; h0 staged in LDS; Horner correction
// + gate fused into Y staging; bf16 MFMA out-proj.
// ---------------------------------------------------------------------------
__global__ __launch_bounds__(256) void ke_out(
    const __bf16* __restrict__ ybh, const float* __restrict__ Sg,
    const __bf16* __restrict__ zgh, const float* __restrict__ Cg,
    const float* __restrict__ h0g, const float* __restrict__ A_log,
    const float* __restrict__ ow, float* __restrict__ out)
{
  __shared__ char sY[16384];
  __shared__ char sW[16384];
  __shared__ float sH[2*128*17];
  __shared__ int s_af[2];
  const int tid = threadIdx.x;
  const int bx = blockIdx.x;
  const int tile = bx & 127; const int b = bx >> 7;
  const int l0 = tile * 32;
  const int q = tid & 31, rg = tid >> 5;
  if (tid < 2) s_af[tid] = 1;
  bool bad0 = false, bad1 = false;
  #pragma unroll
  for (int it=0; it<8; ++it){
    int e = it*256 + tid;
    int n = e & 15;
    float tgt = (float)(n+1);
    float a0 = __expf(A_log[e]);
    float a1 = __expf(A_log[DI*NS + e]);
    if (fabsf(a0 - tgt) > 1e-4f*tgt) bad0 = true;
    if (fabsf(a1 - tgt) > 1e-4f*tgt) bad1 = true;
  }
  {
    const int cch0 = (l0 >> 6), cch1 = ((Lx-1-l0) >> 6);
    #pragma unroll
    for (int it=0; it<4; ++it){
      int f = it*256 + tid;
      int dir = f >> 9, rem = f & 511;
      int dd = rem >> 2, k = rem & 3;
      size_t strm = (size_t)(b*2+dir);
      int cch = dir ? cch1 : cch0;
      float4 v = *(const float4*)&h0g[(((strm*NC)+cch)*DI + dd)*NS + k*4];
      float* hp = &sH[dir*2176 + dd*17 + k*4];
      hp[0]=v.x; hp[1]=v.y; hp[2]=v.z; hp[3]=v.w;
    }
  }
  __syncthreads();
  if (bad0) s_af[0] = 0;
  if (bad1) s_af[1] = 0;
  __syncthreads();
  const bool af0 = (s_af[0] != 0), af1 = (s_af[1] != 0);
  #pragma unroll
  for (int dir=0; dir<2; ++dir){
    const size_t strm = (size_t)(b*2+dir);
    const bool afast = dir ? af1 : af0;
    float h0q[4][16];
    #pragma unroll
    for (int dd=0; dd<4; ++dd){
      const float* hp = &sH[dir*2176 + (q*4+dd)*17];
      #pragma unroll
      for (int n=0;n<16;++n) h0q[dd][n] = hp[n];
    }
    #pragma unroll
    for (int it=0; it<4; ++it){
      int r = it*8 + rg;
      size_t prow = strm*Lx + (size_t)(dir ? (Lx-1-(l0+r)) : (l0+r));
      bf16x4v yb4 = *(const bf16x4v*)&ybh[prow*DI + q*4];
      float4 S4 = *(const float4*)&Sg[prow*DI + q*4];
      bf16x4v zb = *(const bf16x4v*)&zgh[prow*DI + q*4];
      float c16[16];
      #pragma unroll
      for (int k=0;k<4;++k) *(float4*)&c16[k*4] = *(const float4*)&Cg[prow*NS + k*4];
      float yv[4] = {(float)yb4[0],(float)yb4[1],(float)yb4[2],(float)yb4[3]};
      float Sv[4] = {S4.x,S4.y,S4.z,S4.w};
      float zv[4] = {(float)zb[0],(float)zb[1],(float)zb[2],(float)zb[3]};
      bf16x4v hv;
      #pragma unroll
      for (int dd=0; dd<4; ++dd){
        float corr;
        if (afast){
          float e1 = __expf(-Sv[dd]);
          float g[16];
          #pragma unroll
          for (int n=0;n<16;++n) g[n] = c16[n]*h0q[dd][n];
          float t = g[15];
          #pragma unroll
          for (int n=14;n>=0;--n) t = fmaf(t, e1, g[n]);
          corr = t * e1;
        } else {
          corr = 0.f;
          #pragma unroll
          for (int n=0;n<16;++n){
            float an = -__expf(A_log[((size_t)(dir*DI) + q*4+dd)*NS + n]);
            corr = fmaf(__expf(an*Sv[dd])*c16[n], h0q[dd][n], corr);
          }
        }
        float zz = zv[dd];
        float yf = (yv[dd] + corr) * (zz * fsig(zz));
        hv[dd] = (__bf16)yf;
      }
      *(bf16x4v*)(sY + ((r*512 + dir*256 + q*8) ^ ((r&7)<<4))) = hv;
    }
  }
  __syncthreads();
  const int lane = tid & 63, wv = tid >> 6;
  f32x4 acc2[2] = {{0.f,0.f,0.f,0.f},{0.f,0.f,0.f,0.f}};
  #pragma unroll
  for (int dir=0; dir<2; ++dir){
    #pragma unroll
    for (int it=0; it<8; ++it){
      int e = it*256 + tid;
      int c = e >> 5, qq = e & 31;
      float4 w = *(const float4*)(ow + ((size_t)(dir*DM + c))*DI + qq*4);
      bf16x4v hv; hv[0]=(__bf16)w.x; hv[1]=(__bf16)w.y; hv[2]=(__bf16)w.z; hv[3]=(__bf16)w.w;
      *(bf16x4v*)(sW + ((c*256 + qq*8) ^ ((c&7)<<4))) = hv;
    }
    __syncthreads();
    #pragma unroll
    for (int t=0; t<2; ++t){
      int T = wv*2 + t, mt = T >> 2, nt = T & 3;
      #pragma unroll
      for (int ktl=0; ktl<4; ++ktl){
        int row = mt*16 + (lane&15);
        bf16x8v av = *(const bf16x8v*)(sY + ((row*512 + dir*256 + ktl*64 + (lane>>4)*16) ^ ((row&7)<<4)));
        int ch = nt*16 + (lane&15);
        bf16x8v wvv = *(const bf16x8v*)(sW + ((ch*256 + ktl*64 + (lane>>4)*16) ^ ((ch&7)<<4)));
        acc2[t] = __builtin_amdgcn_mfma_f32_16x16x32_bf16(av, wvv, acc2[t], 0,0,0);
      }
    }
    __syncthreads();
  }
  #pragma unroll
  for (int t=0; t<2; ++t){
    int T = wv*2 + t, mt = T >> 2, nt = T & 3;
    #pragma unroll
    for (int r=0; r<4; ++r){
      int m = mt*16 + (lane>>4)*4 + r;
      int ch = nt*16 + (lane&15);
      out[((size_t)b*Lx + (size_t)(l0+m))*DM + ch] = acc2[t][r];
    }
  }
}

extern "C" void kernel_launch(void* const* d_in, const int* in_sizes, int n_in,
                              void* d_out, int out_size, void* d_ws, size_t ws_size,
                              hipStream_t stream)
{
  const float* x      = (const float*)d_in[0];
  const float* ln_g   = (const float*)d_in[1];
  const float* ln_b   = (const float*)d_in[2];
  const float* in_w   = (const float*)d_in[3];
  const float* conv_w = (const float*)d_in[4];
  const float* conv_b = (const float*)d_in[5];
  const float* xp_w   = (const float*)d_in[6];
  const float* dtp_w  = (const float*)d_in[7];
  const float* dt_b   = (const float*)d_in[8];
  const float* A_log  = (const float*)d_in[9];
  const float* Dp     = (const float*)d_in[10];
  const float* ow     = (const float*)d_in[11];
  float* out = (float*)d_out;
  float* ws = (float*)d_ws;
  const size_t NBD = (size_t)Bsz*2*Lx*DI;     // 8,388,608
  const size_t NBN = (size_t)Bsz*2*Lx*NS;     // 1,048,576
  float* xcg = ws;                       // xc -> S (in place, ks_scan)
  float* dtg = xcg + NBD;                // dt (read-only after a1)
  __bf16* zgh = (__bf16*)(dtg + NBD);    // z bf16   (NBD/2 float slots)
  __bf16* ybh = (__bf16*)(dtg + NBD + NBD/2); // y bf16 (NBD/2 float slots)
  float* Bg  = dtg + NBD + NBD;          // after zgh+ybh
  float* Cg  = Bg + NBN;
  float* Pm  = Cg + NBN;                 // chunk P; becomes h0 in-place after kc
  float* he  = out;                      // hend staged in d_out (overwritten by ke)

  a1_front<<<dim3(Bsz*2*(Lx/64)), dim3(512), 0, stream>>>(
      x, ln_g, ln_b, in_w, conv_w, conv_b, xp_w, dtp_w, dt_b, xcg, dtg, zgh, Bg, Cg);
  ks_scan<<<dim3(Bsz*2*NC), dim3(256), 0, stream>>>(dtg, xcg, ybh, Bg, Cg, A_log, Dp, Pm, he);
  kc_pass2<<<dim3(Bsz*2), dim3(256), 0, stream>>>(Pm, he);
  ke_out<<<dim3(Bsz*(Lx/32)), dim3(256), 0, stream>>>(
      ybh, xcg, zgh, Cg, Pm, A_log, ow, out);
}

// Round 27
// 119.281 us; speedup vs baseline: 1.0461x; 1.0018x over previous
//
#include <hip/hip_runtime.h>

#define Bsz 8
#define Lx 4096
#define DM 64
#define DI 128
#define NS 16
#define RK 4
#define KC 4
#define NC 64
#define CT 64

typedef __attribute__((ext_vector_type(8))) __bf16 bf16x8v;
typedef __attribute__((ext_vector_type(4))) __bf16 bf16x4v;
typedef __attribute__((ext_vector_type(2))) __bf16 bf16x2v;
typedef __attribute__((ext_vector_type(4))) float f32x4;

__device__ __forceinline__ float fsig(float x){ return 1.f/(1.f+__expf(-x)); }
__device__ __forceinline__ float dot4(float4 a, float4 b){
  return fmaf(a.x,b.x, fmaf(a.y,b.y, fmaf(a.z,b.z, a.w*b.w)));
}
// powers e1^(n0+1)..e1^(n0+8), log-depth
__device__ __forceinline__ void pow8(float e1, int half, float p[8]){
  float e2=e1*e1, e4=e2*e2, e8=e4*e4;
  if (half){
    p[0]=e8*e1; p[1]=e8*e2; p[2]=p[1]*e1; p[3]=e8*e4;
    p[4]=p[3]*e1; p[5]=p[3]*e2; p[6]=p[5]*e1; p[7]=e8*e8;
  } else {
    p[0]=e1; p[1]=e2; p[2]=e2*e1; p[3]=e4;
    p[4]=e4*e1; p[5]=e4*e2; p[6]=p[5]*e1; p[7]=e8;
  }
}

// ---------------------------------------------------------------------------
// A1 v15: round-25 structure; (dt,xc) packed bf16x2 -> one 4B coalesced store.
// xc re-read from uB (bf16, resident through P6/P7). No fp32 xc/dt globals.
// ---------------------------------------------------------------------------
__global__ __launch_bounds__(512) void a1_front(
    const float* __restrict__ x, const float* __restrict__ ln_g, const float* __restrict__ ln_b,
    const float* __restrict__ in_w, const float* __restrict__ conv_w, const float* __restrict__ conv_b,
    const float* __restrict__ xp_w, const float* __restrict__ dtp_w, const float* __restrict__ dt_b,
    unsigned* __restrict__ dxg, __bf16* __restrict__ zgh,
    float* __restrict__ Bg, float* __restrict__ Cg)
{
  __shared__ float uA[4864];
  __shared__ float uB[4096];
  const int tid = threadIdx.x;
  const int bx = blockIdx.x;
  const int tile = bx & 63;
  const int i = (bx >> 6) & 1;
  const int b = bx >> 7;
  const int l0 = tile * 64;
  const size_t rbase = (size_t)(b*2+i)*Lx + l0;
  const int lane = tid & 63, wv = tid >> 6;

  {
    const float gg = ln_g[lane], bb = ln_b[lane];
    for (int lr = wv; lr < 67; lr += 8) {
      float v = 0.f;
      int l = l0 - 3 + lr;
      if (l >= 0) {
        int pl = i ? (Lx-1-l) : l;
        v = x[((size_t)b*Lx + pl)*DM + lane];
        float s = v, s2 = v*v;
        #pragma unroll
        for (int off=32; off; off>>=1){ s += __shfl_xor(s,off); s2 += __shfl_xor(s2,off); }
        float mu = s * (1.f/DM);
        float rs = rsqrtf(s2*(1.f/DM) - mu*mu + 1e-5f);
        v = (v-mu)*rs*gg + bb;
      }
      *(__bf16*)((char*)uA + ((lr*128 + lane*2) ^ ((lr&7)<<4))) = (__bf16)v;
    }
  }
  __syncthreads();

  f32x4 acc[5][2];
  {
    f32x4 z4v = {0.f, 0.f, 0.f, 0.f};
    #pragma unroll
    for (int mt=0; mt<5; ++mt){ acc[mt][0] = z4v; acc[mt][1] = z4v; }
    #pragma unroll
    for (int p = 0; p < 2; ++p) {
      #pragma unroll
      for (int it=0; it<4; ++it) {
        int g = it*512 + tid;
        int c = g >> 4, q = g & 15;
        float4 w = *(const float4*)(in_w + ((size_t)(i*2*DI) + p*DI + c)*DM + q*4);
        bf16x4v hv;
        hv[0]=(__bf16)w.x; hv[1]=(__bf16)w.y; hv[2]=(__bf16)w.z; hv[3]=(__bf16)w.w;
        *(bf16x4v*)((char*)uB + ((c*128 + q*8) ^ ((c&7)<<4))) = hv;
      }
      __syncthreads();
      bf16x8v bfr[2];
      #pragma unroll
      for (int kt=0; kt<2; ++kt){
        int cl = wv*16 + (lane&15);
        int byt = (cl*128 + kt*64 + (lane>>4)*16) ^ ((cl&7)<<4);
        bfr[kt] = *(const bf16x8v*)((const char*)uB + byt);
      }
      #pragma unroll
      for (int mt=0; mt<5; ++mt){
        bf16x8v afr[2];
        #pragma unroll
        for (int kt=0; kt<2; ++kt){
          int row = mt*16 + (lane&15);
          int byt = (row*128 + kt*64 + (lane>>4)*16) ^ ((row&7)<<4);
          afr[kt] = *(const bf16x8v*)((const char*)uA + byt);
        }
        acc[mt][p] = __builtin_amdgcn_mfma_f32_16x16x32_bf16(afr[0], bfr[0], acc[mt][p], 0,0,0);
        acc[mt][p] = __builtin_amdgcn_mfma_f32_16x16x32_bf16(afr[1], bfr[1], acc[mt][p], 0,0,0);
      }
      __syncthreads();
    }
  }

  {
    const int d0 = wv*16 + (lane&15);
    const int d = tid & 127, rh = tid >> 7;
    const float4 cw = *(const float4*)(conv_w + (size_t)(i*DI + d)*KC);
    const float cb = conv_b[i*DI + d];
    #pragma unroll
    for (int h=0; h<2; ++h) {
      #pragma unroll
      for (int mt=0; mt<5; ++mt)
        #pragma unroll
        for (int r=0; r<4; ++r){
          int m = mt*16 + (lane>>4)*4 + r;
          if (m >= h*32 && m <= h*32+34)
            uA[(m - h*32)*129 + d0] = acc[mt][0][r];
        }
      if (h == 0) {
        #pragma unroll
        for (int mt=0; mt<5; ++mt)
          #pragma unroll
          for (int r=0; r<4; ++r){
            int m = mt*16 + (lane>>4)*4 + r;
            if (m >= 3 && m <= 66)
              zgh[(rbase + (m-3))*DI + d0] = (__bf16)acc[mt][1][r];
          }
      }
      __syncthreads();
      #pragma unroll
      for (int rr=0; rr<8; ++rr){
        int lb = rh*8 + rr;
        int r = h*32 + lb;
        float v0 = uA[(lb  )*129 + d];
        float v1 = uA[(lb+1)*129 + d];
        float v2 = uA[(lb+2)*129 + d];
        float v3 = uA[(lb+3)*129 + d];
        float aa = cb + cw.x*v0 + cw.y*v1 + cw.z*v2 + cw.w*v3;
        float xc = aa * fsig(aa);
        int off = (r*256 + d*2) ^ ((r&7)<<4);
        *(__bf16*)((char*)uB + off) = (__bf16)xc;
      }
      __syncthreads();
    }
  }

  for (int e = tid; e < 36*32; e += 512) {
    int j = e >> 5, k0 = (e & 31)*4;
    float4 w = *(const float4*)(xp_w + ((size_t)(i*36) + j)*DI + k0);
    float vv[4] = {w.x, w.y, w.z, w.w};
    bf16x4v hv, lv;
    #pragma unroll
    for (int k=0;k<4;++k){
      __bf16 hh = (__bf16)vv[k];
      hv[k] = hh;
      lv[k] = (__bf16)(vv[k] - (float)hh);
    }
    int off = (j*256 + k0*2) ^ ((j&7)<<4);
    *(bf16x4v*)((char*)uA + off) = hv;
    *(bf16x4v*)((char*)uA + off + 9216) = lv;
  }
  __syncthreads();

  for (int t = wv; t < 12; t += 8) {
    int mt = t & 3, nt = t >> 2;
    f32x4 a2 = {0.f,0.f,0.f,0.f};
    #pragma unroll
    for (int kt=0; kt<4; ++kt){
      int row = mt*16 + (lane&15);
      int ab = (row*256 + kt*64 + (lane>>4)*16) ^ ((row&7)<<4);
      bf16x8v ah = *(const bf16x8v*)((const char*)uB + ab);
      int col = nt*16 + (lane&15);
      int bby = (col*256 + kt*64 + (lane>>4)*16) ^ ((col&7)<<4);
      bf16x8v bh = *(const bf16x8v*)((const char*)uA + bby);
      bf16x8v bl = *(const bf16x8v*)((const char*)uA + bby + 9216);
      a2 = __builtin_amdgcn_mfma_f32_16x16x32_bf16(ah, bh, a2, 0,0,0);
      a2 = __builtin_amdgcn_mfma_f32_16x16x32_bf16(ah, bl, a2, 0,0,0);
    }
    #pragma unroll
    for (int rg4=0; rg4<4; ++rg4){
      int row = mt*16 + (lane>>4)*4 + rg4;
      int j = nt*16 + (lane&15);
      float val = a2[rg4];
      if (j < 4) uA[4608 + row*4 + j] = val;
      else if (j < 20) Bg[(rbase+row)*NS + (j-4)] = val;
      else if (j < 36) Cg[(rbase+row)*NS + (j-20)] = val;
    }
  }
  __syncthreads();

  // ---- P7: dt = softplus; pack (dt, xc-from-uB) -> 4B store ----
  #pragma unroll 4
  for (int it=0; it<16; ++it) {
    int e = it*512 + tid;
    int r = e >> 7, d = e & 127;
    float4 dl = *(const float4*)&uA[4608 + r*4];
    float4 w  = *(const float4*)(dtp_w + (size_t)(i*DI + d)*RK);
    float a = dt_b[i*DI + d] + dot4(w, dl);
    float dtv = (a > 15.f) ? a : __logf(1.f + __expf(a));
    int off = (r*256 + d*2) ^ ((r&7)<<4);
    __bf16 xcb = *(const __bf16*)((const char*)uB + off);
    bf16x2v pk; pk[0] = (__bf16)dtv; pk[1] = xcb;
    *(bf16x2v*)&dxg[(rbase + r)*DI + d] = pk;
  }
}

// ---------------------------------------------------------------------------
// KS v5: local scan on packed bf16x2 (dt,xc); decode via integer shifts.
// y_local bf16 -> ybh; S fp32 -> Sg. B/C in LDS; packed double-buffer.
// ---------------------------------------------------------------------------
__global__ __launch_bounds__(256) void ks_scan(
    const unsigned* __restrict__ dxg, float* __restrict__ Sg, __bf16* __restrict__ ybh,
    const float* __restrict__ Bg, const float* __restrict__ Cg,
    const float* __restrict__ A_log, const float* __restrict__ Dp,
    float* __restrict__ Pm, float* __restrict__ hend)
{
  __shared__ float sB[CT*NS];
  __shared__ float sC[CT*NS];
  const int tid = threadIdx.x;
  const int bx = blockIdx.x;
  const int c = bx % NC; const int i = (bx/NC)&1; const int b = bx/(2*NC);
  const int d = tid >> 1, half = tid & 1, n0 = half*8;
  const size_t rb = ((size_t)(b*2+i)*Lx + (size_t)c*CT);
  ((float4*)sB)[tid] = ((const float4*)(Bg + rb*NS))[tid];
  ((float4*)sC)[tid] = ((const float4*)(Cg + rb*NS))[tid];
  float a[8], h[8];
  bool afast = true;
  #pragma unroll
  for (int n=0;n<8;++n){
    a[n] = -__expf(A_log[((size_t)(i*DI)+d)*NS + n0+n]);
    float tgt = (float)(n0+n+1);
    afast = afast && (fabsf(a[n] + tgt) <= 1e-4f*tgt);
    h[n] = 0.f;
  }
  const float Dd = Dp[i*DI + d];
  float S = 0.f;
  unsigned cur[4];
  #pragma unroll
  for (int k=0;k<4;++k) cur[k] = dxg[(rb + k)*DI + d];
  __syncthreads();
  for (int r4 = 0; r4 < CT; r4 += 4){
    unsigned nxt[4];
    if (r4 + 4 < CT){
      #pragma unroll
      for (int k=0;k<4;++k) nxt[k] = dxg[(rb + r4 + 4 + k)*DI + d];
    }
    #pragma unroll
    for (int k=0;k<4;++k){
      unsigned u32 = cur[k];
      float dtt = __uint_as_float(u32 << 16);
      float xcv = __uint_as_float(u32 & 0xffff0000u);
      float u = dtt * xcv;
      S += dtt;
      const float* bp = &sB[(r4 + k)*NS + n0];
      const float* cp = &sC[(r4 + k)*NS + n0];
      float4 b0 = *(const float4*)bp;
      float4 b1 = *(const float4*)(bp+4);
      float4 c0 = *(const float4*)cp;
      float4 c1 = *(const float4*)(cp+4);
      float bb[8] = {b0.x,b0.y,b0.z,b0.w,b1.x,b1.y,b1.z,b1.w};
      float cc[8] = {c0.x,c0.y,c0.z,c0.w,c1.x,c1.y,c1.z,c1.w};
      float pA = 0.f, pB = 0.f;
      if (afast){
        float p[8];
        pow8(__expf(-dtt), half, p);
        #pragma unroll
        for (int n=0;n<8;++n){
          h[n] = fmaf(p[n], h[n], u*bb[n]);
          if (n & 1) pB = fmaf(h[n], cc[n], pB); else pA = fmaf(h[n], cc[n], pA);
        }
      } else {
        #pragma unroll
        for (int n=0;n<8;++n){
          float dA = __expf(a[n]*dtt);
          h[n] = fmaf(dA, h[n], u*bb[n]);
          if (n & 1) pB = fmaf(h[n], cc[n], pB); else pA = fmaf(h[n], cc[n], pA);
        }
      }
      float part = pA + pB;
      float y = part + __shfl_xor(part, 1);
      if (half == 0){
        size_t g = (rb + r4 + k)*DI + d;
        ybh[g] = (__bf16)fmaf(xcv, Dd, y);
        Sg[g] = S;
      }
    }
    if (r4 + 4 < CT){
      #pragma unroll
      for (int k=0;k<4;++k) cur[k] = nxt[k];
    }
  }
  size_t ob = (((size_t)(b*2+i)*NC + c)*DI + d)*NS + n0;
  if (afast){
    float p[8];
    pow8(__expf(-S), half, p);
    #pragma unroll
    for (int n=0;n<8;++n) Pm[ob+n] = p[n];
  } else {
    #pragma unroll
    for (int n=0;n<8;++n) Pm[ob+n] = __expf(a[n]*S);
  }
  #pragma unroll
  for (int n=0;n<8;++n) hend[ob+n] = h[n];
}

// ---------------------------------------------------------------------------
// KC v2: chunk propagation with prefetch (in-place h0 over Pm)
// ---------------------------------------------------------------------------
__global__ __launch_bounds__(256) void kc_pass2(
    float* __restrict__ Pm, const float* __restrict__ hend)
{
  const int tid = threadIdx.x;
  const int bi = blockIdx.x;
  const int d = tid>>1, n0 = (tid&1)*8;
  float h[8];
  #pragma unroll
  for (int n=0;n<8;++n) h[n]=0.f;
  const size_t stride = (size_t)DI*NS;
  size_t ob = (((size_t)bi*NC)*DI + d)*NS + n0;
  float4 pa = *(const float4*)&Pm[ob],   pb = *(const float4*)&Pm[ob+4];
  float4 ea = *(const float4*)&hend[ob], eb = *(const float4*)&hend[ob+4];
  for (int c=0; c<NC; ++c){
    size_t obn = ob + stride;
    float4 qa=pa, qb=pb, fa=ea, fb=eb;
    if (c+1 < NC){
      qa = *(const float4*)&Pm[obn];   qb = *(const float4*)&Pm[obn+4];
      fa = *(const float4*)&hend[obn]; fb = *(const float4*)&hend[obn+4];
    }
    *(float4*)&Pm[ob]   = make_float4(h[0],h[1],h[2],h[3]);
    *(float4*)&Pm[ob+4] = make_float4(h[4],h[5],h[6],h[7]);
    h[0]=fmaf(pa.x,h[0],ea.x); h[1]=fmaf(pa.y,h[1],ea.y);
    h[2]=fmaf(pa.z,h[2],ea.z); h[3]=fmaf(pa.w,h[3],ea.w);
    h[4]=fmaf(pb.x,h[4],eb.x); h[5]=fmaf(pb.y,h[5],eb.y);
    h[6]=fmaf(pb.z,h[6],eb.z); h[7]=fmaf(pb.w,h[7],eb.w);
    pa=qa; pb=qb; ea=fa; eb=fb; ob = obn;
  }
}

// ---------------------------------------------------------------------------
// KE v10 (round-26 proven): bf16 y/z reads; h0 staged in LDS; Horner
// correction + gate fused into Y staging; bf16 MFMA out-proj.
// ---------------------------------------------------------------------------
__global__ __launch_bounds__(256) void ke_out(
    const __bf16* __restrict__ ybh, const float* __restrict__ Sg,
    const __bf16* __restrict__ zgh, const float* __restrict__ Cg,
    const float* __restrict__ h0g, const float* __restrict__ A_log,
    const float* __restrict__ ow, float* __restrict__ out)
{
  __shared__ char sY[16384];
  __shared__ char sW[16384];
  __shared__ float sH[2*128*17];
  __shared__ int s_af[2];
  const int tid = threadIdx.x;
  const int bx = blockIdx.x;
  const int tile = bx & 127; const int b = bx >> 7;
  const int l0 = tile * 32;
  const int q = tid & 31, rg = tid >> 5;
  if (tid < 2) s_af[tid] = 1;
  bool bad0 = false, bad1 = false;
  #pragma unroll
  for (int it=0; it<8; ++it){
    int e = it*256 + tid;
    int n = e & 15;
    float tgt = (float)(n+1);
    float a0 = __expf(A_log[e]);
    float a1 = __expf(A_log[DI*NS + e]);
    if (fabsf(a0 - tgt) > 1e-4f*tgt) bad0 = true;
    if (fabsf(a1 - tgt) > 1e-4f*tgt) bad1 = true;
  }
  {
    const int cch0 = (l0 >> 6), cch1 = ((Lx-1-l0) >> 6);
    #pragma unroll
    for (int it=0; it<4; ++it){
      int f = it*256 + tid;
      int dir = f >> 9, rem = f & 511;
      int dd = rem >> 2, k = rem & 3;
      size_t strm = (size_t)(b*2+dir);
      int cch = dir ? cch1 : cch0;
      float4 v = *(const float4*)&h0g[(((strm*NC)+cch)*DI + dd)*NS + k*4];
      float* hp = &sH[dir*2176 + dd*17 + k*4];
      hp[0]=v.x; hp[1]=v.y; hp[2]=v.z; hp[3]=v.w;
    }
  }
  __syncthreads();
  if (bad0) s_af[0] = 0;
  if (bad1) s_af[1] = 0;
  __syncthreads();
  const bool af0 = (s_af[0] != 0), af1 = (s_af[1] != 0);
  #pragma unroll
  for (int dir=0; dir<2; ++dir){
    const size_t strm = (size_t)(b*2+dir);
    const bool afast = dir ? af1 : af0;
    float h0q[4][16];
    #pragma unroll
    for (int dd=0; dd<4; ++dd){
      const float* hp = &sH[dir*2176 + (q*4+dd)*17];
      #pragma unroll
      for (int n=0;n<16;++n) h0q[dd][n] = hp[n];
    }
    #pragma unroll
    for (int it=0; it<4; ++it){
      int r = it*8 + rg;
      size_t prow = strm*Lx + (size_t)(dir ? (Lx-1-(l0+r)) : (l0+r));
      bf16x4v yb4 = *(const bf16x4v*)&ybh[prow*DI + q*4];
      float4 S4 = *(const float4*)&Sg[prow*DI + q*4];
      bf16x4v zb = *(const bf16x4v*)&zgh[prow*DI + q*4];
      float c16[16];
      #pragma unroll
      for (int k=0;k<4;++k) *(float4*)&c16[k*4] = *(const float4*)&Cg[prow*NS + k*4];
      float yv[4] = {(float)yb4[0],(float)yb4[1],(float)yb4[2],(float)yb4[3]};
      float Sv[4] = {S4.x,S4.y,S4.z,S4.w};
      float zv[4] = {(float)zb[0],(float)zb[1],(float)zb[2],(float)zb[3]};
      bf16x4v hv;
      #pragma unroll
      for (int dd=0; dd<4; ++dd){
        float corr;
        if (afast){
          float e1 = __expf(-Sv[dd]);
          float g[16];
          #pragma unroll
          for (int n=0;n<16;++n) g[n] = c16[n]*h0q[dd][n];
          float t = g[15];
          #pragma unroll
          for (int n=14;n>=0;--n) t = fmaf(t, e1, g[n]);
          corr = t * e1;
        } else {
          corr = 0.f;
          #pragma unroll
          for (int n=0;n<16;++n){
            float an = -__expf(A_log[((size_t)(dir*DI) + q*4+dd)*NS + n]);
            corr = fmaf(__expf(an*Sv[dd])*c16[n], h0q[dd][n], corr);
          }
        }
        float zz = zv[dd];
        float yf = (yv[dd] + corr) * (zz * fsig(zz));
        hv[dd] = (__bf16)yf;
      }
      *(bf16x4v*)(sY + ((r*512 + dir*256 + q*8) ^ ((r&7)<<4))) = hv;
    }
  }
  __syncthreads();
  const int lane = tid & 63, wv = tid >> 6;
  f32x4 acc2[2] = {{0.f,0.f,0.f,0.f},{0.f,0.f,0.f,0.f}};
  #pragma unroll
  for (int dir=0; dir<2; ++dir){
    #pragma unroll
    for (int it=0; it<8; ++it){
      int e = it*256 + tid;
      int c = e >> 5, qq = e & 31;
      float4 w = *(const float4*)(ow + ((size_t)(dir*DM + c))*DI + qq*4);
      bf16x4v hv; hv[0]=(__bf16)w.x; hv[1]=(__bf16)w.y; hv[2]=(__bf16)w.z; hv[3]=(__bf16)w.w;
      *(bf16x4v*)(sW + ((c*256 + qq*8) ^ ((c&7)<<4))) = hv;
    }
    __syncthreads();
    #pragma unroll
    for (int t=0; t<2; ++t){
      int T = wv*2 + t, mt = T >> 2, nt = T & 3;
      #pragma unroll
      for (int ktl=0; ktl<4; ++ktl){
        int row = mt*16 + (lane&15);
        bf16x8v av = *(const bf16x8v*)(sY + ((row*512 + dir*256 + ktl*64 + (lane>>4)*16) ^ ((row&7)<<4)));
        int ch = nt*16 + (lane&15);
        bf16x8v wvv = *(const bf16x8v*)(sW + ((ch*256 + ktl*64 + (lane>>4)*16) ^ ((ch&7)<<4)));
        acc2[t] = __builtin_amdgcn_mfma_f32_16x16x32_bf16(av, wvv, acc2[t], 0,0,0);
      }
    }
    __syncthreads();
  }
  #pragma unroll
  for (int t=0; t<2; ++t){
    int T = wv*2 + t, mt = T >> 2, nt = T & 3;
    #pragma unroll
    for (int r=0; r<4; ++r){
      int m = mt*16 + (lane>>4)*4 + r;
      int ch = nt*16 + (lane&15);
      out[((size_t)b*Lx + (size_t)(l0+m))*DM + ch] = acc2[t][r];
    }
  }
}

extern "C" void kernel_launch(void* const* d_in, const int* in_sizes, int n_in,
                              void* d_out, int out_size, void* d_ws, size_t ws_size,
                              hipStream_t stream)
{
  const float* x      = (const float*)d_in[0];
  const float* ln_g   = (const float*)d_in[1];
  const float* ln_b   = (const float*)d_in[2];
  const float* in_w   = (const float*)d_in[3];
  const float* conv_w = (const float*)d_in[4];
  const float* conv_b = (const float*)d_in[5];
  const float* xp_w   = (const float*)d_in[6];
  const float* dtp_w  = (const float*)d_in[7];
  const float* dt_b   = (const float*)d_in[8];
  const float* A_log  = (const float*)d_in[9];
  const float* Dp     = (const float*)d_in[10];
  const float* ow     = (const float*)d_in[11];
  float* out = (float*)d_out;
  float* ws = (float*)d_ws;
  const size_t NBD = (size_t)Bsz*2*Lx*DI;     // 8,388,608
  const size_t NBN = (size_t)Bsz*2*Lx*NS;     // 1,048,576
  float* Sg  = ws;                         // S fp32 (ks -> ke)
  unsigned* dxg = (unsigned*)(ws + NBD);   // packed (dt,xc) bf16x2, NBD words
  __bf16* zgh = (__bf16*)(ws + 2*NBD);     // z bf16
  __bf16* ybh = (__bf16*)(ws + 2*NBD + NBD/2); // y bf16
  float* Bg  = ws + 3*NBD;
  float* Cg  = Bg + NBN;
  float* Pm  = Cg + NBN;                   // chunk P; becomes h0 in-place after kc
  float* he  = out;                        // hend staged in d_out (overwritten by ke)

  a1_front<<<dim3(Bsz*2*(Lx/64)), dim3(512), 0, stream>>>(
      x, ln_g, ln_b, in_w, conv_w, conv_b, xp_w, dtp_w, dt_b, dxg, zgh, Bg, Cg);
  ks_scan<<<dim3(Bsz*2*NC), dim3(256), 0, stream>>>(dxg, Sg, ybh, Bg, Cg, A_log, Dp, Pm, he);
  kc_pass2<<<dim3(Bsz*2), dim3(256), 0, stream>>>(Pm, he);
  ke_out<<<dim3(Bsz*(Lx/32)), dim3(256), 0, stream>>>(
      ybh, Sg, zgh, Cg, Pm, A_log, ow, out);
}